// Round 2
// baseline (27560.324 us; speedup 1.0000x reference)
//
#include <hip/hip_runtime.h>
#include <math.h>

#define BB 128
#define TT 512
#define DD 512
#define HH 512
#define NN (BB*TT)   // 65536
#define PP 512
#define AA 32
#define CH 64        // timesteps per chunk
#define CR (BB*CH)   // rows per chunk per net = 8192

typedef unsigned short u16;
typedef unsigned int   u32;
typedef __attribute__((ext_vector_type(8))) short short8;
typedef __attribute__((ext_vector_type(4))) float f32x4;

__device__ __forceinline__ u16 f2bf(float f){
    u32 x = __float_as_uint(f);
    u32 r = (x + 0x7fffu + ((x >> 16) & 1u)) >> 16;   // RNE
    return (u16)r;
}
__device__ __forceinline__ float bf2f(u16 u){
    return __uint_as_float(((u32)u) << 16);
}
__device__ __forceinline__ f32x4 mfma16(short8 a, short8 b, f32x4 c){
    return __builtin_amdgcn_mfma_f32_16x16x32_bf16(a, b, c, 0, 0, 0);
}
__device__ __forceinline__ float sigm(float x){
    return 1.f/(1.f + __expf(-x));
}
__device__ __forceinline__ float tanh_f(float x){
    return 1.f - 2.f/(1.f + __expf(2.f*x));
}

// Device-scope grid barrier (plain-launch persistent kernel; all 256 blocks
// are guaranteed co-resident: 64.3KB LDS -> 2 blocks/CU max, 256 blocks on
// 256 CUs => capacity 512 >= 256, so no deadlock is possible).
// One fresh (pre-zeroed) counter per step: no reset race across graph replays.
// This mirrors ROCm's own grid_group::sync (atomic + agent fences).
__device__ __forceinline__ void grid_barrier(unsigned* bar, unsigned nblk){
    __syncthreads();
    if (threadIdx.x == 0){
        __threadfence();   // release: publish h/ys/c writes device-wide
        __hip_atomic_fetch_add(bar, 1u, __ATOMIC_ACQ_REL, __HIP_MEMORY_SCOPE_AGENT);
        while (__hip_atomic_load(bar, __ATOMIC_ACQUIRE, __HIP_MEMORY_SCOPE_AGENT) < nblk)
            __builtin_amdgcn_s_sleep(1);
    }
    __syncthreads();
    __threadfence();       // acquire: invalidate stale lines before h reads
}

// ---------------------------------------------------------------------------
// prep: permute+split LSTM weights. Both Wih and Whh PERMUTED: col c=u*4+g
// <- src row g*512+u. biasP permuted bih+bhh.
// ---------------------------------------------------------------------------
__global__ __launch_bounds__(256) void prep_lstm_w(
    const float* __restrict__ Wih_pi, const float* __restrict__ Whh_pi,
    const float* __restrict__ bih_pi, const float* __restrict__ bhh_pi,
    const float* __restrict__ Wih_vf, const float* __restrict__ Whh_vf,
    const float* __restrict__ bih_vf, const float* __restrict__ bhh_vf,
    u16* __restrict__ wihHi, u16* __restrict__ wihLo,
    u16* __restrict__ whhHi, u16* __restrict__ whhLo,
    float* __restrict__ biasP)
{
    long i = (long)blockIdx.x*256 + threadIdx.x;
    if (i >= 2L*2048*512) return;
    int L = (int)(i >> 20);
    int rem = (int)(i & 1048575);
    int c = rem >> 9, k = rem & 511;
    int u = c >> 2, g = c & 3;
    long src = (long)(g*512 + u)*512 + k;
    float wih = (L ? Wih_vf : Wih_pi)[src];
    float whh = (L ? Whh_vf : Whh_pi)[src];
    u16 h1 = f2bf(wih); wihHi[i] = h1; wihLo[i] = f2bf(wih - bf2f(h1));
    u16 h2 = f2bf(whh); whhHi[i] = h2; whhLo[i] = f2bf(whh - bf2f(h2));
    if (k == 0) {
        float b = (L ? bih_vf : bih_pi)[g*512+u] + (L ? bhh_vf : bhh_pi)[g*512+u];
        biasP[L*2048 + c] = b;
    }
}

// prep MLP weight planes: mat 0=w1pi 1=w1vf 2=w2pi 3=w2vf
__global__ __launch_bounds__(256) void prep_mlp_w(
    const float* __restrict__ w1pi, const float* __restrict__ w1vf,
    const float* __restrict__ w2pi, const float* __restrict__ w2vf,
    const float* __restrict__ b1pi, const float* __restrict__ b1vf,
    const float* __restrict__ b2pi, const float* __restrict__ b2vf,
    u16* __restrict__ mHi, u16* __restrict__ mLo, float* __restrict__ biasM)
{
    long i = (long)blockIdx.x*256 + threadIdx.x;
    if (i >= 4L*262144) return;
    int mat = (int)(i >> 18);
    int rem = (int)(i & 262143);
    const float* src = mat==0 ? w1pi : mat==1 ? w1vf : mat==2 ? w2pi : w2vf;
    float v = src[rem];
    u16 h = f2bf(v); mHi[i] = h; mLo[i] = f2bf(v - bf2f(h));
    if (rem < 512) {
        const float* bs = mat==0 ? b1pi : mat==1 ? b1vf : mat==2 ? b2pi : b2vf;
        biasM[mat*512 + rem] = bs[rem];
    }
}

// init: h planes [L][p=0][e][u] pre-masked; cT transposed [L][u][e] pre-masked;
// startsT [t][e]; zero the 512 per-step barrier counters.
__global__ __launch_bounds__(256) void init_state_k(
    const float* __restrict__ h0_pi, const float* __restrict__ c0_pi,
    const float* __restrict__ h0_vf, const float* __restrict__ c0_vf,
    const float* __restrict__ starts,
    u16* __restrict__ hHi, u16* __restrict__ hLo, float* __restrict__ cT,
    float* __restrict__ startsT, unsigned* __restrict__ bar)
{
    int i = blockIdx.x*256 + threadIdx.x;
    if (i < 512) bar[i] = 0u;
    if (i < NN) {
        int e = i >> 9, t = i & 511;
        startsT[t*128 + e] = starts[i];
    }
    if (i >= 2*BB*HH) return;
    int L = i >> 16; int r = i & 65535;
    int e = r >> 9, u = r & 511;
    float m = 1.0f - starts[(long)e*TT];
    float h = (L ? h0_vf : h0_pi)[r] * m;
    float c = (L ? c0_vf : c0_pi)[r] * m;
    long hidx = (long)(L*2)*65536 + r;    // [L][parity=0][e][u]
    u16 hh = f2bf(h);
    hHi[hidx] = hh; hLo[hidx] = f2bf(h - bf2f(hh));
    cT[(long)L*65536 + (long)u*128 + e] = c;
}

// ---------------------------------------------------------------------------
// generic K=512 split-bf16 GEMM, tile 128x128, 256 threads (4 waves, 64x64)
// AM: 0 = A fp32 (converted in staging)
//     1 = A hi/lo planes
// row map: arow = (m>>rowSh)*rowOuterHi + (m&mask)*rowOuterLo + rowBase
// EM: 0 = +bias -> fp32 out   1 = +bias,relu -> planes   2 = +bias -> planes
// ---------------------------------------------------------------------------
template<int AM, int EM>
__global__ __launch_bounds__(256) void gemm_k512(
    const float* __restrict__ Afp,
    const u16* __restrict__ aHi, const u16* __restrict__ aLo, long aZ,
    int rowSh, int rowOuterHi, int rowOuterLo, int rowBase,
    const u16* __restrict__ bHi, const u16* __restrict__ bLo, long bZ,
    const float* __restrict__ bias, long biasZ,
    float* __restrict__ outF, long outFZ, int outLd,
    u16* __restrict__ oHi, u16* __restrict__ oLo, long oZ)
{
    __shared__ u16 sAh[5120], sAl[5120], sBh[5120], sBl[5120];  // 128 x 40 each
    const int tid = threadIdx.x;
    const int z = blockIdx.z;
    const long Mbase = (long)blockIdx.x * 128;
    const long Nbase = (long)blockIdx.y * 128;
    const int r2 = tid >> 1, half = tid & 1;
    const long mstage = Mbase + r2;
    const long arow = (mstage >> rowSh) * (long)rowOuterHi
                    + (mstage & (((long)1<<rowSh)-1)) * (long)rowOuterLo + rowBase;
    const long brow = Nbase + r2;
    const int wid = tid >> 6, lane = tid & 63;
    const int mh = wid & 1, nh = wid >> 1;
    const int l15 = lane & 15, quad = lane >> 4;

    f32x4 acc[4][4];
    #pragma unroll
    for (int i = 0; i < 4; ++i)
        #pragma unroll
        for (int j = 0; j < 4; ++j)
            acc[i][j] = (f32x4){0.f,0.f,0.f,0.f};

    const int sOffW = r2*40 + half*16;

    for (int kt = 0; kt < 16; ++kt) {
        const int k0 = kt*32;
        if constexpr (AM == 0) {
            const float* ap = Afp + arow*512 + k0 + half*16;
            float fv[16];
            #pragma unroll
            for (int q = 0; q < 4; ++q) *(float4*)(fv + q*4) = ((const float4*)ap)[q];
            short8 vh0, vh1, vl0, vl1;
            #pragma unroll
            for (int i = 0; i < 8; ++i){
                u16 h  = f2bf(fv[i]);   vh0[i] = (short)h;  vl0[i] = (short)f2bf(fv[i]   - bf2f(h));
                u16 h2 = f2bf(fv[8+i]); vh1[i] = (short)h2; vl1[i] = (short)f2bf(fv[8+i] - bf2f(h2));
            }
            *(short8*)(sAh + sOffW) = vh0; *(short8*)(sAh + sOffW + 8) = vh1;
            *(short8*)(sAl + sOffW) = vl0; *(short8*)(sAl + sOffW + 8) = vl1;
        } else {
            const u16* ph = aHi + (long)z*aZ + arow*512 + k0 + half*16;
            const u16* pl = aLo + (long)z*aZ + arow*512 + k0 + half*16;
            *(short8*)(sAh + sOffW) = *(const short8*)ph;
            *(short8*)(sAh + sOffW + 8) = *(const short8*)(ph + 8);
            *(short8*)(sAl + sOffW) = *(const short8*)pl;
            *(short8*)(sAl + sOffW + 8) = *(const short8*)(pl + 8);
        }
        {
            const u16* ph = bHi + (long)z*bZ + brow*512 + k0 + half*16;
            const u16* pl = bLo + (long)z*bZ + brow*512 + k0 + half*16;
            *(short8*)(sBh + sOffW) = *(const short8*)ph;
            *(short8*)(sBh + sOffW + 8) = *(const short8*)(ph + 8);
            *(short8*)(sBl + sOffW) = *(const short8*)pl;
            *(short8*)(sBl + sOffW + 8) = *(const short8*)(pl + 8);
        }
        __syncthreads();
        short8 bh[4], bl[4];
        #pragma unroll
        for (int nt = 0; nt < 4; ++nt){
            int bo = (nh*64 + nt*16 + l15)*40 + quad*8;
            bh[nt] = *(const short8*)(sBh + bo);
            bl[nt] = *(const short8*)(sBl + bo);
        }
        #pragma unroll
        for (int mt = 0; mt < 4; ++mt){
            int ao = (mh*64 + mt*16 + l15)*40 + quad*8;
            short8 ah = *(const short8*)(sAh + ao);
            short8 al = *(const short8*)(sAl + ao);
            #pragma unroll
            for (int nt = 0; nt < 4; ++nt){
                acc[mt][nt] = mfma16(ah, bh[nt], acc[mt][nt]);
                acc[mt][nt] = mfma16(ah, bl[nt], acc[mt][nt]);
                acc[mt][nt] = mfma16(al, bh[nt], acc[mt][nt]);
            }
        }
        __syncthreads();
    }
    #pragma unroll
    for (int nt = 0; nt < 4; ++nt){
        const long col = Nbase + nh*64 + nt*16 + l15;
        const float bv = bias[(long)z*biasZ + col];
        #pragma unroll
        for (int mt = 0; mt < 4; ++mt){
            const long rowm = Mbase + mh*64 + mt*16 + quad*4;
            #pragma unroll
            for (int rr = 0; rr < 4; ++rr){
                float v = acc[mt][nt][rr] + bv;
                const long m = rowm + rr;
                if constexpr (EM == 0) {
                    outF[(long)z*outFZ + m*(long)outLd + col] = v;
                } else {
                    if constexpr (EM == 1) v = fmaxf(v, 0.f);
                    u16 h = f2bf(v);
                    u16 l = f2bf(v - bf2f(h));
                    oHi[(long)z*oZ + m*512 + col] = h;
                    oLo[(long)z*oZ + m*512 + col] = l;
                }
            }
        }
    }
}

// ---------------------------------------------------------------------------
// Persistent LSTM chunk: 64 recurrent steps in ONE plain launch.
// grid (64 wc, 2 eb, 2 L) = 256 blocks x 256 threads (4 waves).
// Whh panel staged to LDS ONCE per chunk (was: once per step = 16MB/step).
// cT lives in registers across the chunk (block-stationary units).
// One hand-rolled device barrier per step orders the cross-block h exchange:
// step t reads parity p=t&1 and writes 1-p, so the single barrier covers both
// the RAW on parity 1-p and the WAR on parity p. Arithmetic order identical
// to the per-step kernel (bit-identical results).
// ---------------------------------------------------------------------------
__global__ __launch_bounds__(256) void lstm_chunk(
    u16* __restrict__ hHi, u16* __restrict__ hLo,           // [L][2][128][512]
    const u16* __restrict__ whhHi, const u16* __restrict__ whhLo, // [L][2048][512] permuted
    const float* __restrict__ gx,                            // [L][tau][128][2048]
    const float* __restrict__ startsT,                       // [t][128]
    float* __restrict__ cT,                                  // [L][512][128]
    u16* __restrict__ ysHi, u16* __restrict__ ysLo,          // [L][tau][128][512]
    float* __restrict__ dout, unsigned* __restrict__ bar, int t0)
{
    __shared__ __attribute__((aligned(16))) u16 sA[2][16384];  // [plane][kt][wcol][32k]
    __shared__ float zsm[4][144];

    const int tid  = threadIdx.x;
    const int wc   = blockIdx.x;         // 0..63 : 32 gate-cols
    const int eb   = blockIdx.y;         // 0..1  : 64-env half
    const int L    = blockIdx.z;
    const int wid  = tid >> 6, lane = tid & 63;
    const int l15  = lane & 15, quad = lane >> 4;
    const int ebase = eb*64;
    const int e    = ebase + wid*16 + l15;       // this lane's env (as B row)

    // ---- stage Whh' panel ONCE: 32 wcols x 512 k x hi/lo = 64 KB
    {
        const size_t wbase = (size_t)L*1048576 + (size_t)(wc*32)*512;
        #pragma unroll
        for (int i = 0; i < 16; ++i){
            int f = tid + i*256;          // 0..4095
            int pl = f >> 11;
            int r2 = f & 2047;
            int wcol = r2 >> 6, ksg = r2 & 63;
            const u16* src = (pl ? whhLo : whhHi) + wbase + (size_t)wcol*512 + ksg*8;
            int dst = (ksg>>2)*1024 + wcol*32 + (ksg&3)*8;
            *(short8*)(sA[pl] + dst) = *(const short8*)src;
        }
    }
    __syncthreads();

    // ---- cT in registers for the whole chunk (block-stationary ownership)
    const int u0 = wc*8 + quad;          // mt=0 unit
    const int u1 = wc*8 + 4 + quad;      // mt=1 unit
    const size_t ci0 = (size_t)L*65536 + (size_t)u0*128 + e;
    const size_t ci1 = (size_t)L*65536 + (size_t)u1*128 + e;
    float c0 = cT[ci0];
    float c1 = cT[ci1];

    const size_t hrowOff = (size_t)e*512 + quad*8;
    const size_t gxbase  = ((size_t)L*CR + e)*2048 + wc*32 + quad*4;

    for (int tau = 0; tau < CH; ++tau){
        const int t = t0 + tau;
        const int p = t & 1;

        // prefetch gx (HBM) + mask before the K-loop so latency hides under MFMA
        const float* gp = gx + gxbase + (size_t)tau*(128*2048);
        float4 gv0 = *(const float4*)(gp);
        float4 gv1 = *(const float4*)(gp + 16);
        const float mn = (t < TT-1) ? (1.0f - startsT[(t+1)*128 + e]) : 1.0f;

        // ---- K loop: acc = gates (i,f,g,o in regs) for unit wc*8+mt*4+quad, env l15
        const u16* hHiP = hHi + (size_t)(L*2+p)*65536 + hrowOff;
        const u16* hLoP = hLo + (size_t)(L*2+p)*65536 + hrowOff;
        f32x4 acc0 = (f32x4){0.f,0.f,0.f,0.f};
        f32x4 acc1 = (f32x4){0.f,0.f,0.f,0.f};
        #pragma unroll
        for (int kt = 0; kt < 16; ++kt){
            short8 bh = *(const short8*)(hHiP + kt*32);
            short8 bl = *(const short8*)(hLoP + kt*32);
            int a0 = kt*1024 + l15*32 + quad*8;          // mt=0 rows l15, mt=1 rows 16+l15
            short8 ah0 = *(const short8*)(sA[0] + a0);
            short8 al0 = *(const short8*)(sA[1] + a0);
            short8 ah1 = *(const short8*)(sA[0] + a0 + 512);
            short8 al1 = *(const short8*)(sA[1] + a0 + 512);
            acc0 = mfma16(ah0, bh, acc0);
            acc0 = mfma16(ah0, bl, acc0);
            acc0 = mfma16(al0, bh, acc0);
            acc1 = mfma16(ah1, bh, acc1);
            acc1 = mfma16(ah1, bl, acc1);
            acc1 = mfma16(al1, bh, acc1);
        }

        // ---- gates -> state update (env = l15, unit = quad, gates = regs)
        {
            float ii = sigm(acc0[0] + gv0.x);
            float ff = sigm(acc0[1] + gv0.y);
            float gg = tanh_f(acc0[2] + gv0.z);
            float oo = sigm(acc0[3] + gv0.w);
            float cn = ff*c0 + ii*gg;
            float hn = oo * tanh_f(cn);
            c0 = cn * mn;
            zsm[wid][l15*8 + quad] = hn;
            zsm[wid][128 + l15] = mn;
            if (t == TT-1) {
                dout[(size_t)(3+2*L)*NN + (size_t)e*512 + u0] = hn;
                dout[(size_t)(4+2*L)*NN + (size_t)e*512 + u0] = cn;
            }
        }
        {
            float ii = sigm(acc1[0] + gv1.x);
            float ff = sigm(acc1[1] + gv1.y);
            float gg = tanh_f(acc1[2] + gv1.z);
            float oo = sigm(acc1[3] + gv1.w);
            float cn = ff*c1 + ii*gg;
            float hn = oo * tanh_f(cn);
            c1 = cn * mn;
            zsm[wid][l15*8 + 4 + quad] = hn;
            if (t == TT-1) {
                dout[(size_t)(3+2*L)*NN + (size_t)e*512 + u1] = hn;
                dout[(size_t)(4+2*L)*NN + (size_t)e*512 + u1] = cn;
            }
        }
        __syncthreads();

        // ---- coalesced h / ys writes: role = quad (0:hHi 1:hLo 2:ysHi 3:ysLo)
        {
            const int role = quad;
            const int e2 = l15;
            const int eg = ebase + wid*16 + e2;
            float v[8];
            #pragma unroll
            for (int j = 0; j < 8; ++j) v[j] = zsm[wid][e2*8 + j];
            const float mn2 = zsm[wid][128 + e2];
            short8 pk;
            if (role < 2) {
                #pragma unroll
                for (int j = 0; j < 8; ++j){
                    float hm = v[j] * mn2;
                    u16 h = f2bf(hm);
                    pk[j] = (short)(role == 0 ? h : f2bf(hm - bf2f(h)));
                }
                u16* dst = (role == 0 ? hHi : hLo)
                         + (size_t)(L*2 + (1-p))*65536 + (size_t)eg*512 + wc*8;
                *(short8*)dst = pk;
            } else {
                #pragma unroll
                for (int j = 0; j < 8; ++j){
                    u16 h = f2bf(v[j]);
                    pk[j] = (short)(role == 2 ? h : f2bf(v[j] - bf2f(h)));
                }
                u16* dst = (role == 2 ? ysHi : ysLo)
                         + ((size_t)L*CR + (size_t)tau*128 + eg)*512 + wc*8;
                *(short8*)dst = pk;
            }
        }

        // one device-wide barrier per step (skip after last step: the kernel
        // boundary orders the hand-off to the MLP GEMMs / next chunk)
        if (tau < CH-1) grid_barrier(bar + t0 + tau, 256u);
    }

    cT[ci0] = c0;
    cT[ci1] = c1;
}

// ---------------------------------------------------------------------------
// heads: chunk row m = tau*128 + e  ->  n = e*TT + t0 + tau
// ---------------------------------------------------------------------------
__global__ __launch_bounds__(256) void head_pi(
    const u16* __restrict__ latHi, const u16* __restrict__ latLo,
    const float* __restrict__ actor_w, const float* __restrict__ actor_b,
    float* __restrict__ dout, int t0)
{
    __shared__ float latS[16*516];
    __shared__ float lg[16*36];
    const int tid = threadIdx.x;
    const long r0 = (long)blockIdx.x * 16;
    {
        int rr = tid >> 4, seg = tid & 15;
        const u16* ph = latHi + (r0 + rr)*512 + seg*32;
        const u16* pl = latLo + (r0 + rr)*512 + seg*32;
        float* dst = latS + rr*516 + seg*32;
        #pragma unroll
        for (int ii = 0; ii < 4; ++ii){
            short8 vh = *(const short8*)(ph + ii*8);
            short8 vl = *(const short8*)(pl + ii*8);
            #pragma unroll
            for (int jj = 0; jj < 8; ++jj)
                dst[ii*8+jj] = bf2f((u16)vh[jj]) + bf2f((u16)vl[jj]);
        }
    }
    __syncthreads();
    {
        int rr = tid >> 4, a0 = (tid & 15)*2;
        const float4* lrow = (const float4*)(latS + rr*516);
        float acc0 = actor_b[a0], acc1 = actor_b[a0+1];
        for (int kq = 0; kq < 128; ++kq){
            float4 lv = lrow[kq];
            float4 w0 = ((const float4*)actor_w)[(a0  )*128 + kq];
            float4 w1 = ((const float4*)actor_w)[(a0+1)*128 + kq];
            acc0 += lv.x*w0.x + lv.y*w0.y + lv.z*w0.z + lv.w*w0.w;
            acc1 += lv.x*w1.x + lv.y*w1.y + lv.z*w1.z + lv.w*w1.w;
        }
        lg[rr*36 + a0]   = acc0;
        lg[rr*36 + a0+1] = acc1;
    }
    __syncthreads();
    if (tid < 16){
        float mx = -INFINITY; int am = 0;
        #pragma unroll
        for (int a = 0; a < AA; ++a){
            float v = lg[tid*36 + a];
            if (v > mx){ mx = v; am = a; }
        }
        float se = 0.f;
        #pragma unroll
        for (int a = 0; a < AA; ++a) se += expf(lg[tid*36 + a] - mx);
        long row = r0 + tid;
        long n = (row & 127)*TT + t0 + (row >> 7);
        dout[n] = (float)am;
        dout[2L*NN + n] = -logf(se);
    }
}

__global__ __launch_bounds__(256) void head_vf(
    const u16* __restrict__ latHi, const u16* __restrict__ latLo,
    const float* __restrict__ critic_w, const float* __restrict__ critic_b,
    float* __restrict__ dout, int t0)
{
    __shared__ float part[256];
    const int tid = threadIdx.x;
    const long r0 = (long)blockIdx.x * 32;
    int rr = tid >> 3, seg = tid & 7;
    const u16* ph = latHi + (r0 + rr)*512 + seg*64;
    const u16* pl = latLo + (r0 + rr)*512 + seg*64;
    float acc = 0.f;
    #pragma unroll
    for (int ii = 0; ii < 8; ++ii){
        short8 vh = *(const short8*)(ph + ii*8);
        short8 vl = *(const short8*)(pl + ii*8);
        #pragma unroll
        for (int jj = 0; jj < 8; ++jj){
            float lv = bf2f((u16)vh[jj]) + bf2f((u16)vl[jj]);
            acc += lv * critic_w[seg*64 + ii*8 + jj];
        }
    }
    part[tid] = acc;
    __syncthreads();
    if (tid < 32){
        float v = critic_b[0];
        #pragma unroll
        for (int s = 0; s < 8; ++s) v += part[tid*8 + s];
        long row = r0 + tid;
        long n = (row & 127)*TT + t0 + (row >> 7);
        dout[(long)NN + n] = v;
    }
}

// ---------------------------------------------------------------------------
extern "C" void kernel_launch(void* const* d_in, const int* in_sizes, int n_in,
                              void* d_out, int out_size, void* d_ws, size_t ws_size,
                              hipStream_t stream) {
    const float* features = (const float*)d_in[0];
    const float* starts   = (const float*)d_in[1];
    const float* h0_pi = (const float*)d_in[2];
    const float* c0_pi = (const float*)d_in[3];
    const float* h0_vf = (const float*)d_in[4];
    const float* c0_vf = (const float*)d_in[5];
    const float* Wih_pi = (const float*)d_in[6];
    const float* Whh_pi = (const float*)d_in[7];
    const float* bih_pi = (const float*)d_in[8];
    const float* bhh_pi = (const float*)d_in[9];
    const float* Wih_vf = (const float*)d_in[10];
    const float* Whh_vf = (const float*)d_in[11];
    const float* bih_vf = (const float*)d_in[12];
    const float* bhh_vf = (const float*)d_in[13];
    const float* pol_w1 = (const float*)d_in[14];
    const float* pol_b1 = (const float*)d_in[15];
    const float* pol_w2 = (const float*)d_in[16];
    const float* pol_b2 = (const float*)d_in[17];
    const float* val_w1 = (const float*)d_in[18];
    const float* val_b1 = (const float*)d_in[19];
    const float* val_w2 = (const float*)d_in[20];
    const float* val_b2 = (const float*)d_in[21];
    const float* actor_w  = (const float*)d_in[22];
    const float* actor_b  = (const float*)d_in[23];
    const float* critic_w = (const float*)d_in[24];
    const float* critic_b = (const float*)d_in[25];
    float* out = (float*)d_out;

    size_t off = 0;
    auto alloc = [&](size_t b) {
        void* p = (char*)d_ws + off;
        off += (b + 255) & ~(size_t)255;
        return p;
    };
    u16* wihHi = (u16*)alloc(2L*2048*512*2);
    u16* wihLo = (u16*)alloc(2L*2048*512*2);
    u16* whhHi = (u16*)alloc(2L*2048*512*2);
    u16* whhLo = (u16*)alloc(2L*2048*512*2);
    float* biasP = (float*)alloc(2L*2048*4);
    u16* mHi = (u16*)alloc(4L*262144*2);
    u16* mLo = (u16*)alloc(4L*262144*2);
    float* biasM = (float*)alloc(4L*512*4);
    u16* hHi = (u16*)alloc(2L*2*128*512*2);
    u16* hLo = (u16*)alloc(2L*2*128*512*2);
    float* cT  = (float*)alloc(2L*128*512*4);
    float* startsT = (float*)alloc((size_t)NN*4);
    unsigned* bar = (unsigned*)alloc(512*4);
    u16* ysHi = (u16*)alloc(2L*CR*512*2);
    u16* ysLo = (u16*)alloc(2L*CR*512*2);
    u16* hidHi = (u16*)alloc(2L*CR*512*2);
    u16* hidLo = (u16*)alloc(2L*CR*512*2);
    u16* latHi = (u16*)alloc(2L*CR*512*2);
    u16* latLo = (u16*)alloc(2L*CR*512*2);
    float* gxF = (float*)alloc(2L*CR*2048*4);     // [L][tau][128][2048], 134 MB
    const long gxZ = (long)CR*2048;               // per-net stride
    const long pZ  = (long)CR*512;                // plane per-net stride

    prep_lstm_w<<<dim3(8192), dim3(256), 0, stream>>>(
        Wih_pi, Whh_pi, bih_pi, bhh_pi, Wih_vf, Whh_vf, bih_vf, bhh_vf,
        wihHi, wihLo, whhHi, whhLo, biasP);
    prep_mlp_w<<<dim3(4096), dim3(256), 0, stream>>>(
        pol_w1, val_w1, pol_w2, val_w2, pol_b1, val_b1, pol_b2, val_b2,
        mHi, mLo, biasM);
    init_state_k<<<dim3(512), dim3(256), 0, stream>>>(
        h0_pi, c0_pi, h0_vf, c0_vf, starts, hHi, hLo, cT, startsT, bar);

    for (int t0 = 0; t0 < TT; t0 += CH) {
        // gx[L][tau][e][2048] = x @ Wih'^T + (bih+bhh); out row m = tau*128+e,
        // feature row = e*512 + t0 + tau  -> arow = (m&127)*512 + (m>>7) + t0
        gemm_k512<0,0><<<dim3(CR/128, 16, 2), dim3(256), 0, stream>>>(
            features, nullptr, nullptr, 0L,
            7, 1, 512, t0,
            wihHi, wihLo, 1048576L,
            biasP, 2048L,
            gxF, gxZ, 2048,
            nullptr, nullptr, 0L);
        // 64 recurrent steps in ONE persistent plain launch (hand barrier)
        lstm_chunk<<<dim3(64, 2, 2), dim3(256), 0, stream>>>(
            hHi, hLo, whhHi, whhLo, gxF, startsT, cT, ysHi, ysLo,
            out, bar, t0);
        // MLP layers on the chunk (rows = tau*128+e, identity map)
        gemm_k512<1,1><<<dim3(CR/128, 4, 2), dim3(256), 0, stream>>>(
            nullptr, ysHi, ysLo, pZ,
            30, 0, 1, 0,
            mHi, mLo, 262144L,
            biasM, 512L,
            nullptr, 0L, 0,
            hidHi, hidLo, pZ);
        gemm_k512<1,2><<<dim3(CR/128, 4, 2), dim3(256), 0, stream>>>(
            nullptr, hidHi, hidLo, pZ,
            30, 0, 1, 0,
            mHi + 2L*262144, mLo + 2L*262144, 262144L,
            biasM + 1024, 512L,
            nullptr, 0L, 0,
            latHi, latLo, pZ);
        head_pi<<<dim3(CR/16), dim3(256), 0, stream>>>(
            latHi, latLo, actor_w, actor_b, out, t0);
        head_vf<<<dim3(CR/32), dim3(256), 0, stream>>>(
            latHi + pZ, latLo + pZ, critic_w, critic_b, out, t0);
    }
}

// Round 4
// 16839.798 us; speedup vs baseline: 1.6366x; 1.6366x over previous
//
#include <hip/hip_runtime.h>
#include <math.h>

#define BB 128
#define TT 512
#define DD 512
#define HH 512
#define NN (BB*TT)   // 65536
#define PP 512
#define AA 32
#define CH 64        // timesteps per chunk
#define CR (BB*CH)   // rows per chunk per net = 8192

typedef unsigned short u16;
typedef unsigned int   u32;
typedef __attribute__((ext_vector_type(8))) short short8;
typedef __attribute__((ext_vector_type(4))) float f32x4;

__device__ __forceinline__ u16 f2bf(float f){
    u32 x = __float_as_uint(f);
    u32 r = (x + 0x7fffu + ((x >> 16) & 1u)) >> 16;   // RNE
    return (u16)r;
}
__device__ __forceinline__ float bf2f(u16 u){
    return __uint_as_float(((u32)u) << 16);
}
__device__ __forceinline__ f32x4 mfma16(short8 a, short8 b, f32x4 c){
    return __builtin_amdgcn_mfma_f32_16x16x32_bf16(a, b, c, 0, 0, 0);
}
__device__ __forceinline__ float sigm(float x){
    return 1.f/(1.f + __expf(-x));
}
__device__ __forceinline__ float tanh_f(float x){
    return 1.f - 2.f/(1.f + __expf(2.f*x));
}

// Group barrier with CORRECT release/acquire semantics but NO per-poll cache
// maintenance (round 2's acquire-spin invalidated L2 every poll -> 49us/step;
// round 3's fence-free version raced -> stale h).
//  release: each thread drains stores to L2 (vmcnt), thread0 __threadfence()
//           (buffer_wbl2 sc1: L2 -> MALL, completion via vmcnt) BEFORE arrive.
//  arrive/spin: relaxed agent atomics (MALL RMW / plain bypass load, zero
//           cache-maintenance instructions while spinning).
//  acquire: one __threadfence() (buffer_inv) after spin exit, so this CU's
//           subsequent h loads re-fetch fresh lines from MALL.
// Domain = the 64 wc-blocks sharing (eb,L): h never crosses domains.
__device__ __forceinline__ void group_barrier(unsigned* cnt, unsigned nblk){
    asm volatile("s_waitcnt vmcnt(0)" ::: "memory");  // my stores reached L2
    __syncthreads();
    if (threadIdx.x == 0){
        __threadfence();   // release: wbl2 -> MALL (tracked), + inv
        __hip_atomic_fetch_add(cnt, 1u, __ATOMIC_RELAXED, __HIP_MEMORY_SCOPE_AGENT);
        while (__hip_atomic_load(cnt, __ATOMIC_RELAXED, __HIP_MEMORY_SCOPE_AGENT) < nblk)
            __builtin_amdgcn_s_sleep(2);
        __threadfence();   // acquire: invalidate stale L1/L2 lines once
    }
    __syncthreads();
    asm volatile("" ::: "memory");
}

// ---------------------------------------------------------------------------
// prep: permute+split LSTM weights. Both Wih and Whh PERMUTED: col c=u*4+g
// <- src row g*512+u. biasP permuted bih+bhh.
// ---------------------------------------------------------------------------
__global__ __launch_bounds__(256) void prep_lstm_w(
    const float* __restrict__ Wih_pi, const float* __restrict__ Whh_pi,
    const float* __restrict__ bih_pi, const float* __restrict__ bhh_pi,
    const float* __restrict__ Wih_vf, const float* __restrict__ Whh_vf,
    const float* __restrict__ bih_vf, const float* __restrict__ bhh_vf,
    u16* __restrict__ wihHi, u16* __restrict__ wihLo,
    u16* __restrict__ whhHi, u16* __restrict__ whhLo,
    float* __restrict__ biasP)
{
    long i = (long)blockIdx.x*256 + threadIdx.x;
    if (i >= 2L*2048*512) return;
    int L = (int)(i >> 20);
    int rem = (int)(i & 1048575);
    int c = rem >> 9, k = rem & 511;
    int u = c >> 2, g = c & 3;
    long src = (long)(g*512 + u)*512 + k;
    float wih = (L ? Wih_vf : Wih_pi)[src];
    float whh = (L ? Whh_vf : Whh_pi)[src];
    u16 h1 = f2bf(wih); wihHi[i] = h1; wihLo[i] = f2bf(wih - bf2f(h1));
    u16 h2 = f2bf(whh); whhHi[i] = h2; whhLo[i] = f2bf(whh - bf2f(h2));
    if (k == 0) {
        float b = (L ? bih_vf : bih_pi)[g*512+u] + (L ? bhh_vf : bhh_pi)[g*512+u];
        biasP[L*2048 + c] = b;
    }
}

// prep MLP weight planes: mat 0=w1pi 1=w1vf 2=w2pi 3=w2vf
__global__ __launch_bounds__(256) void prep_mlp_w(
    const float* __restrict__ w1pi, const float* __restrict__ w1vf,
    const float* __restrict__ w2pi, const float* __restrict__ w2vf,
    const float* __restrict__ b1pi, const float* __restrict__ b1vf,
    const float* __restrict__ b2pi, const float* __restrict__ b2vf,
    u16* __restrict__ mHi, u16* __restrict__ mLo, float* __restrict__ biasM)
{
    long i = (long)blockIdx.x*256 + threadIdx.x;
    if (i >= 4L*262144) return;
    int mat = (int)(i >> 18);
    int rem = (int)(i & 262143);
    const float* src = mat==0 ? w1pi : mat==1 ? w1vf : mat==2 ? w2pi : w2vf;
    float v = src[rem];
    u16 h = f2bf(v); mHi[i] = h; mLo[i] = f2bf(v - bf2f(h));
    if (rem < 512) {
        const float* bs = mat==0 ? b1pi : mat==1 ? b1vf : mat==2 ? b2pi : b2vf;
        biasM[mat*512 + rem] = bs[rem];
    }
}

// init: h planes [L][p=0][e][u] pre-masked; cT transposed [L][u][e] pre-masked;
// startsT [t][e]; zero the per-(step,group) barrier counters.
__global__ __launch_bounds__(256) void init_state_k(
    const float* __restrict__ h0_pi, const float* __restrict__ c0_pi,
    const float* __restrict__ h0_vf, const float* __restrict__ c0_vf,
    const float* __restrict__ starts,
    u16* __restrict__ hHi, u16* __restrict__ hLo, float* __restrict__ cT,
    float* __restrict__ startsT, unsigned* __restrict__ bar)
{
    int i = blockIdx.x*256 + threadIdx.x;
    if (i < 2048) bar[i] = 0u;
    if (i < NN) {
        int e = i >> 9, t = i & 511;
        startsT[t*128 + e] = starts[i];
    }
    if (i >= 2*BB*HH) return;
    int L = i >> 16; int r = i & 65535;
    int e = r >> 9, u = r & 511;
    float m = 1.0f - starts[(long)e*TT];
    float h = (L ? h0_vf : h0_pi)[r] * m;
    float c = (L ? c0_vf : c0_pi)[r] * m;
    long hidx = (long)(L*2)*65536 + r;    // [L][parity=0][e][u]
    u16 hh = f2bf(h);
    hHi[hidx] = hh; hLo[hidx] = f2bf(h - bf2f(hh));
    cT[(long)L*65536 + (long)u*128 + e] = c;
}

// ---------------------------------------------------------------------------
// generic K=512 split-bf16 GEMM, tile 128x128, 256 threads (4 waves, 64x64)
// AM: 0 = A fp32 (converted in staging)
//     1 = A hi/lo planes
// row map: arow = (m>>rowSh)*rowOuterHi + (m&mask)*rowOuterLo + rowBase
// EM: 0 = +bias -> fp32 out   1 = +bias,relu -> planes   2 = +bias -> planes
// ---------------------------------------------------------------------------
template<int AM, int EM>
__global__ __launch_bounds__(256) void gemm_k512(
    const float* __restrict__ Afp,
    const u16* __restrict__ aHi, const u16* __restrict__ aLo, long aZ,
    int rowSh, int rowOuterHi, int rowOuterLo, int rowBase,
    const u16* __restrict__ bHi, const u16* __restrict__ bLo, long bZ,
    const float* __restrict__ bias, long biasZ,
    float* __restrict__ outF, long outFZ, int outLd,
    u16* __restrict__ oHi, u16* __restrict__ oLo, long oZ)
{
    __shared__ u16 sAh[5120], sAl[5120], sBh[5120], sBl[5120];  // 128 x 40 each
    const int tid = threadIdx.x;
    const int z = blockIdx.z;
    const long Mbase = (long)blockIdx.x * 128;
    const long Nbase = (long)blockIdx.y * 128;
    const int r2 = tid >> 1, half = tid & 1;
    const long mstage = Mbase + r2;
    const long arow = (mstage >> rowSh) * (long)rowOuterHi
                    + (mstage & (((long)1<<rowSh)-1)) * (long)rowOuterLo + rowBase;
    const long brow = Nbase + r2;
    const int wid = tid >> 6, lane = tid & 63;
    const int mh = wid & 1, nh = wid >> 1;
    const int l15 = lane & 15, quad = lane >> 4;

    f32x4 acc[4][4];
    #pragma unroll
    for (int i = 0; i < 4; ++i)
        #pragma unroll
        for (int j = 0; j < 4; ++j)
            acc[i][j] = (f32x4){0.f,0.f,0.f,0.f};

    const int sOffW = r2*40 + half*16;

    for (int kt = 0; kt < 16; ++kt) {
        const int k0 = kt*32;
        if constexpr (AM == 0) {
            const float* ap = Afp + arow*512 + k0 + half*16;
            float fv[16];
            #pragma unroll
            for (int q = 0; q < 4; ++q) *(float4*)(fv + q*4) = ((const float4*)ap)[q];
            short8 vh0, vh1, vl0, vl1;
            #pragma unroll
            for (int i = 0; i < 8; ++i){
                u16 h  = f2bf(fv[i]);   vh0[i] = (short)h;  vl0[i] = (short)f2bf(fv[i]   - bf2f(h));
                u16 h2 = f2bf(fv[8+i]); vh1[i] = (short)h2; vl1[i] = (short)f2bf(fv[8+i] - bf2f(h2));
            }
            *(short8*)(sAh + sOffW) = vh0; *(short8*)(sAh + sOffW + 8) = vh1;
            *(short8*)(sAl + sOffW) = vl0; *(short8*)(sAl + sOffW + 8) = vl1;
        } else {
            const u16* ph = aHi + (long)z*aZ + arow*512 + k0 + half*16;
            const u16* pl = aLo + (long)z*aZ + arow*512 + k0 + half*16;
            *(short8*)(sAh + sOffW) = *(const short8*)ph;
            *(short8*)(sAh + sOffW + 8) = *(const short8*)(ph + 8);
            *(short8*)(sAl + sOffW) = *(const short8*)pl;
            *(short8*)(sAl + sOffW + 8) = *(const short8*)(pl + 8);
        }
        {
            const u16* ph = bHi + (long)z*bZ + brow*512 + k0 + half*16;
            const u16* pl = bLo + (long)z*bZ + brow*512 + k0 + half*16;
            *(short8*)(sBh + sOffW) = *(const short8*)ph;
            *(short8*)(sBh + sOffW + 8) = *(const short8*)(ph + 8);
            *(short8*)(sBl + sOffW) = *(const short8*)pl;
            *(short8*)(sBl + sOffW + 8) = *(const short8*)(pl + 8);
        }
        __syncthreads();
        short8 bh[4], bl[4];
        #pragma unroll
        for (int nt = 0; nt < 4; ++nt){
            int bo = (nh*64 + nt*16 + l15)*40 + quad*8;
            bh[nt] = *(const short8*)(sBh + bo);
            bl[nt] = *(const short8*)(sBl + bo);
        }
        #pragma unroll
        for (int mt = 0; mt < 4; ++mt){
            int ao = (mh*64 + mt*16 + l15)*40 + quad*8;
            short8 ah = *(const short8*)(sAh + ao);
            short8 al = *(const short8*)(sAl + ao);
            #pragma unroll
            for (int nt = 0; nt < 4; ++nt){
                acc[mt][nt] = mfma16(ah, bh[nt], acc[mt][nt]);
                acc[mt][nt] = mfma16(ah, bl[nt], acc[mt][nt]);
                acc[mt][nt] = mfma16(al, bh[nt], acc[mt][nt]);
            }
        }
        __syncthreads();
    }
    #pragma unroll
    for (int nt = 0; nt < 4; ++nt){
        const long col = Nbase + nh*64 + nt*16 + l15;
        const float bv = bias[(long)z*biasZ + col];
        #pragma unroll
        for (int mt = 0; mt < 4; ++mt){
            const long rowm = Mbase + mh*64 + mt*16 + quad*4;
            #pragma unroll
            for (int rr = 0; rr < 4; ++rr){
                float v = acc[mt][nt][rr] + bv;
                const long m = rowm + rr;
                if constexpr (EM == 0) {
                    outF[(long)z*outFZ + m*(long)outLd + col] = v;
                } else {
                    if constexpr (EM == 1) v = fmaxf(v, 0.f);
                    u16 h = f2bf(v);
                    u16 l = f2bf(v - bf2f(h));
                    oHi[(long)z*oZ + m*512 + col] = h;
                    oLo[(long)z*oZ + m*512 + col] = l;
                }
            }
        }
    }
}

// ---------------------------------------------------------------------------
// Persistent LSTM chunk: 64 recurrent steps in ONE plain launch.
// grid (64 wc, 2 eb, 2 L) = 256 blocks x 256 threads (4 waves).
// Whh panel staged to LDS ONCE per chunk. cT in registers across the chunk.
// All data plain/cached (L2 serves the 64x h read redundancy). One fenced
// group barrier per step over the 64 wc-blocks sharing (eb,L); step t reads
// parity p=t&1, writes 1-p, so a single barrier covers RAW+WAR. Arithmetic
// order identical to the per-step kernel (bit-identical results).
// ---------------------------------------------------------------------------
__global__ __launch_bounds__(256) void lstm_chunk(
    u16* __restrict__ hHi, u16* __restrict__ hLo,           // [L][2][128][512]
    const u16* __restrict__ whhHi, const u16* __restrict__ whhLo, // [L][2048][512] permuted
    const float* __restrict__ gx,                            // [L][tau][128][2048]
    const float* __restrict__ startsT,                       // [t][128]
    float* __restrict__ cT,                                  // [L][512][128]
    u16* __restrict__ ysHi, u16* __restrict__ ysLo,          // [L][tau][128][512]
    float* __restrict__ dout, unsigned* __restrict__ bar, int t0)
{
    __shared__ __attribute__((aligned(16))) u16 sA[2][16384];  // [plane][kt][wcol][32k]
    __shared__ float zsm[4][144];

    const int tid  = threadIdx.x;
    const int wc   = blockIdx.x;         // 0..63 : 32 gate-cols
    const int eb   = blockIdx.y;         // 0..1  : 64-env half
    const int L    = blockIdx.z;
    const int wid  = tid >> 6, lane = tid & 63;
    const int l15  = lane & 15, quad = lane >> 4;
    const int ebase = eb*64;
    const int e    = ebase + wid*16 + l15;       // this lane's env (as B row)
    const int grp  = L*2 + eb;                   // barrier domain (64 blocks)

    // ---- stage Whh' panel ONCE: 32 wcols x 512 k x hi/lo = 64 KB
    {
        const size_t wbase = (size_t)L*1048576 + (size_t)(wc*32)*512;
        #pragma unroll
        for (int i = 0; i < 16; ++i){
            int f = tid + i*256;          // 0..4095
            int pl = f >> 11;
            int r2 = f & 2047;
            int wcol = r2 >> 6, ksg = r2 & 63;
            const u16* src = (pl ? whhLo : whhHi) + wbase + (size_t)wcol*512 + ksg*8;
            int dst = (ksg>>2)*1024 + wcol*32 + (ksg&3)*8;
            *(short8*)(sA[pl] + dst) = *(const short8*)src;
        }
    }
    __syncthreads();

    // ---- cT in registers for the whole chunk (block-stationary ownership)
    const int u0 = wc*8 + quad;          // mt=0 unit
    const int u1 = wc*8 + 4 + quad;      // mt=1 unit
    const size_t ci0 = (size_t)L*65536 + (size_t)u0*128 + e;
    const size_t ci1 = (size_t)L*65536 + (size_t)u1*128 + e;
    float c0 = cT[ci0];
    float c1 = cT[ci1];

    const size_t hrowOff = (size_t)e*512 + quad*8;
    const size_t gxbase  = ((size_t)L*CR + e)*2048 + wc*32 + quad*4;

    for (int tau = 0; tau < CH; ++tau){
        const int t = t0 + tau;
        const int p = t & 1;

        // prefetch gx (HBM) + mask before the K-loop so latency hides under MFMA
        const float* gp = gx + gxbase + (size_t)tau*(128*2048);
        float4 gv0 = *(const float4*)(gp);
        float4 gv1 = *(const float4*)(gp + 16);
        const float mn = (t < TT-1) ? (1.0f - startsT[(t+1)*128 + e]) : 1.0f;

        // ---- K loop: acc = gates (i,f,g,o in regs) for unit wc*8+mt*4+quad, env l15
        const u16* hHiP = hHi + (size_t)(L*2+p)*65536 + hrowOff;
        const u16* hLoP = hLo + (size_t)(L*2+p)*65536 + hrowOff;
        f32x4 acc0 = (f32x4){0.f,0.f,0.f,0.f};
        f32x4 acc1 = (f32x4){0.f,0.f,0.f,0.f};
        #pragma unroll
        for (int kt = 0; kt < 16; ++kt){
            short8 bh = *(const short8*)(hHiP + kt*32);
            short8 bl = *(const short8*)(hLoP + kt*32);
            int a0 = kt*1024 + l15*32 + quad*8;          // mt=0 rows l15, mt=1 rows 16+l15
            short8 ah0 = *(const short8*)(sA[0] + a0);
            short8 al0 = *(const short8*)(sA[1] + a0);
            short8 ah1 = *(const short8*)(sA[0] + a0 + 512);
            short8 al1 = *(const short8*)(sA[1] + a0 + 512);
            acc0 = mfma16(ah0, bh, acc0);
            acc0 = mfma16(ah0, bl, acc0);
            acc0 = mfma16(al0, bh, acc0);
            acc1 = mfma16(ah1, bh, acc1);
            acc1 = mfma16(ah1, bl, acc1);
            acc1 = mfma16(al1, bh, acc1);
        }

        // ---- gates -> state update (env = l15, unit = quad, gates = regs)
        {
            float ii = sigm(acc0[0] + gv0.x);
            float ff = sigm(acc0[1] + gv0.y);
            float gg = tanh_f(acc0[2] + gv0.z);
            float oo = sigm(acc0[3] + gv0.w);
            float cn = ff*c0 + ii*gg;
            float hn = oo * tanh_f(cn);
            c0 = cn * mn;
            zsm[wid][l15*8 + quad] = hn;
            zsm[wid][128 + l15] = mn;
            if (t == TT-1) {
                dout[(size_t)(3+2*L)*NN + (size_t)e*512 + u0] = hn;
                dout[(size_t)(4+2*L)*NN + (size_t)e*512 + u0] = cn;
            }
        }
        {
            float ii = sigm(acc1[0] + gv1.x);
            float ff = sigm(acc1[1] + gv1.y);
            float gg = tanh_f(acc1[2] + gv1.z);
            float oo = sigm(acc1[3] + gv1.w);
            float cn = ff*c1 + ii*gg;
            float hn = oo * tanh_f(cn);
            c1 = cn * mn;
            zsm[wid][l15*8 + 4 + quad] = hn;
            if (t == TT-1) {
                dout[(size_t)(3+2*L)*NN + (size_t)e*512 + u1] = hn;
                dout[(size_t)(4+2*L)*NN + (size_t)e*512 + u1] = cn;
            }
        }
        __syncthreads();

        // ---- coalesced h / ys writes: role = quad (0:hHi 1:hLo 2:ysHi 3:ysLo)
        {
            const int role = quad;
            const int e2 = l15;
            const int eg = ebase + wid*16 + e2;
            float v[8];
            #pragma unroll
            for (int j = 0; j < 8; ++j) v[j] = zsm[wid][e2*8 + j];
            const float mn2 = zsm[wid][128 + e2];
            short8 pk;
            if (role < 2) {
                #pragma unroll
                for (int j = 0; j < 8; ++j){
                    float hm = v[j] * mn2;
                    u16 h = f2bf(hm);
                    pk[j] = (short)(role == 0 ? h : f2bf(hm - bf2f(h)));
                }
                u16* dst = (role == 0 ? hHi : hLo)
                         + (size_t)(L*2 + (1-p))*65536 + (size_t)eg*512 + wc*8;
                *(short8*)dst = pk;
            } else {
                #pragma unroll
                for (int j = 0; j < 8; ++j){
                    u16 h = f2bf(v[j]);
                    pk[j] = (short)(role == 2 ? h : f2bf(v[j] - bf2f(h)));
                }
                u16* dst = (role == 2 ? ysHi : ysLo)
                         + ((size_t)L*CR + (size_t)tau*128 + eg)*512 + wc*8;
                *(short8*)dst = pk;
            }
        }

        // one fenced group barrier per step (skip after last step: the kernel
        // boundary orders the hand-off to the MLP GEMMs / next chunk)
        if (tau < CH-1) group_barrier(bar + (t0 + tau)*4 + grp, 64u);
    }

    cT[ci0] = c0;
    cT[ci1] = c1;
}

// ---------------------------------------------------------------------------
// heads: chunk row m = tau*128 + e  ->  n = e*TT + t0 + tau
// ---------------------------------------------------------------------------
__global__ __launch_bounds__(256) void head_pi(
    const u16* __restrict__ latHi, const u16* __restrict__ latLo,
    const float* __restrict__ actor_w, const float* __restrict__ actor_b,
    float* __restrict__ dout, int t0)
{
    __shared__ float latS[16*516];
    __shared__ float lg[16*36];
    const int tid = threadIdx.x;
    const long r0 = (long)blockIdx.x * 16;
    {
        int rr = tid >> 4, seg = tid & 15;
        const u16* ph = latHi + (r0 + rr)*512 + seg*32;
        const u16* pl = latLo + (r0 + rr)*512 + seg*32;
        float* dst = latS + rr*516 + seg*32;
        #pragma unroll
        for (int ii = 0; ii < 4; ++ii){
            short8 vh = *(const short8*)(ph + ii*8);
            short8 vl = *(const short8*)(pl + ii*8);
            #pragma unroll
            for (int jj = 0; jj < 8; ++jj)
                dst[ii*8+jj] = bf2f((u16)vh[jj]) + bf2f((u16)vl[jj]);
        }
    }
    __syncthreads();
    {
        int rr = tid >> 4, a0 = (tid & 15)*2;
        const float4* lrow = (const float4*)(latS + rr*516);
        float acc0 = actor_b[a0], acc1 = actor_b[a0+1];
        for (int kq = 0; kq < 128; ++kq){
            float4 lv = lrow[kq];
            float4 w0 = ((const float4*)actor_w)[(a0  )*128 + kq];
            float4 w1 = ((const float4*)actor_w)[(a0+1)*128 + kq];
            acc0 += lv.x*w0.x + lv.y*w0.y + lv.z*w0.z + lv.w*w0.w;
            acc1 += lv.x*w1.x + lv.y*w1.y + lv.z*w1.z + lv.w*w1.w;
        }
        lg[rr*36 + a0]   = acc0;
        lg[rr*36 + a0+1] = acc1;
    }
    __syncthreads();
    if (tid < 16){
        float mx = -INFINITY; int am = 0;
        #pragma unroll
        for (int a = 0; a < AA; ++a){
            float v = lg[tid*36 + a];
            if (v > mx){ mx = v; am = a; }
        }
        float se = 0.f;
        #pragma unroll
        for (int a = 0; a < AA; ++a) se += expf(lg[tid*36 + a] - mx);
        long row = r0 + tid;
        long n = (row & 127)*TT + t0 + (row >> 7);
        dout[n] = (float)am;
        dout[2L*NN + n] = -logf(se);
    }
}

__global__ __launch_bounds__(256) void head_vf(
    const u16* __restrict__ latHi, const u16* __restrict__ latLo,
    const float* __restrict__ critic_w, const float* __restrict__ critic_b,
    float* __restrict__ dout, int t0)
{
    __shared__ float part[256];
    const int tid = threadIdx.x;
    const long r0 = (long)blockIdx.x * 32;
    int rr = tid >> 3, seg = tid & 7;
    const u16* ph = latHi + (r0 + rr)*512 + seg*64;
    const u16* pl = latLo + (r0 + rr)*512 + seg*64;
    float acc = 0.f;
    #pragma unroll
    for (int ii = 0; ii < 8; ++ii){
        short8 vh = *(const short8*)(ph + ii*8);
        short8 vl = *(const short8*)(pl + ii*8);
        #pragma unroll
        for (int jj = 0; jj < 8; ++jj){
            float lv = bf2f((u16)vh[jj]) + bf2f((u16)vl[jj]);
            acc += lv * critic_w[seg*64 + ii*8 + jj];
        }
    }
    part[tid] = acc;
    __syncthreads();
    if (tid < 32){
        float v = critic_b[0];
        #pragma unroll
        for (int s = 0; s < 8; ++s) v += part[tid*8 + s];
        long row = r0 + tid;
        long n = (row & 127)*TT + t0 + (row >> 7);
        dout[(long)NN + n] = v;
    }
}

// ---------------------------------------------------------------------------
extern "C" void kernel_launch(void* const* d_in, const int* in_sizes, int n_in,
                              void* d_out, int out_size, void* d_ws, size_t ws_size,
                              hipStream_t stream) {
    const float* features = (const float*)d_in[0];
    const float* starts   = (const float*)d_in[1];
    const float* h0_pi = (const float*)d_in[2];
    const float* c0_pi = (const float*)d_in[3];
    const float* h0_vf = (const float*)d_in[4];
    const float* c0_vf = (const float*)d_in[5];
    const float* Wih_pi = (const float*)d_in[6];
    const float* Whh_pi = (const float*)d_in[7];
    const float* bih_pi = (const float*)d_in[8];
    const float* bhh_pi = (const float*)d_in[9];
    const float* Wih_vf = (const float*)d_in[10];
    const float* Whh_vf = (const float*)d_in[11];
    const float* bih_vf = (const float*)d_in[12];
    const float* bhh_vf = (const float*)d_in[13];
    const float* pol_w1 = (const float*)d_in[14];
    const float* pol_b1 = (const float*)d_in[15];
    const float* pol_w2 = (const float*)d_in[16];
    const float* pol_b2 = (const float*)d_in[17];
    const float* val_w1 = (const float*)d_in[18];
    const float* val_b1 = (const float*)d_in[19];
    const float* val_w2 = (const float*)d_in[20];
    const float* val_b2 = (const float*)d_in[21];
    const float* actor_w  = (const float*)d_in[22];
    const float* actor_b  = (const float*)d_in[23];
    const float* critic_w = (const float*)d_in[24];
    const float* critic_b = (const float*)d_in[25];
    float* out = (float*)d_out;

    size_t off = 0;
    auto alloc = [&](size_t b) {
        void* p = (char*)d_ws + off;
        off += (b + 255) & ~(size_t)255;
        return p;
    };
    u16* wihHi = (u16*)alloc(2L*2048*512*2);
    u16* wihLo = (u16*)alloc(2L*2048*512*2);
    u16* whhHi = (u16*)alloc(2L*2048*512*2);
    u16* whhLo = (u16*)alloc(2L*2048*512*2);
    float* biasP = (float*)alloc(2L*2048*4);
    u16* mHi = (u16*)alloc(4L*262144*2);
    u16* mLo = (u16*)alloc(4L*262144*2);
    float* biasM = (float*)alloc(4L*512*4);
    u16* hHi = (u16*)alloc(2L*2*128*512*2);
    u16* hLo = (u16*)alloc(2L*2*128*512*2);
    float* cT  = (float*)alloc(2L*128*512*4);
    float* startsT = (float*)alloc((size_t)NN*4);
    unsigned* bar = (unsigned*)alloc(2048*4);
    u16* ysHi = (u16*)alloc(2L*CR*512*2);
    u16* ysLo = (u16*)alloc(2L*CR*512*2);
    u16* hidHi = (u16*)alloc(2L*CR*512*2);
    u16* hidLo = (u16*)alloc(2L*CR*512*2);
    u16* latHi = (u16*)alloc(2L*CR*512*2);
    u16* latLo = (u16*)alloc(2L*CR*512*2);
    float* gxF = (float*)alloc(2L*CR*2048*4);     // [L][tau][128][2048], 134 MB
    const long gxZ = (long)CR*2048;               // per-net stride
    const long pZ  = (long)CR*512;                // plane per-net stride

    prep_lstm_w<<<dim3(8192), dim3(256), 0, stream>>>(
        Wih_pi, Whh_pi, bih_pi, bhh_pi, Wih_vf, Whh_vf, bih_vf, bhh_vf,
        wihHi, wihLo, whhHi, whhLo, biasP);
    prep_mlp_w<<<dim3(4096), dim3(256), 0, stream>>>(
        pol_w1, val_w1, pol_w2, val_w2, pol_b1, val_b1, pol_b2, val_b2,
        mHi, mLo, biasM);
    init_state_k<<<dim3(512), dim3(256), 0, stream>>>(
        h0_pi, c0_pi, h0_vf, c0_vf, starts, hHi, hLo, cT, startsT, bar);

    for (int t0 = 0; t0 < TT; t0 += CH) {
        // gx[L][tau][e][2048] = x @ Wih'^T + (bih+bhh); out row m = tau*128+e,
        // feature row = e*512 + t0 + tau  -> arow = (m&127)*512 + (m>>7) + t0
        gemm_k512<0,0><<<dim3(CR/128, 16, 2), dim3(256), 0, stream>>>(
            features, nullptr, nullptr, 0L,
            7, 1, 512, t0,
            wihHi, wihLo, 1048576L,
            biasP, 2048L,
            gxF, gxZ, 2048,
            nullptr, nullptr, 0L);
        // 64 recurrent steps in ONE persistent plain launch (fenced barrier)
        lstm_chunk<<<dim3(64, 2, 2), dim3(256), 0, stream>>>(
            hHi, hLo, whhHi, whhLo, gxF, startsT, cT, ysHi, ysLo,
            out, bar, t0);
        // MLP layers on the chunk (rows = tau*128+e, identity map)
        gemm_k512<1,1><<<dim3(CR/128, 4, 2), dim3(256), 0, stream>>>(
            nullptr, ysHi, ysLo, pZ,
            30, 0, 1, 0,
            mHi, mLo, 262144L,
            biasM, 512L,
            nullptr, 0L, 0,
            hidHi, hidLo, pZ);
        gemm_k512<1,2><<<dim3(CR/128, 4, 2), dim3(256), 0, stream>>>(
            nullptr, hidHi, hidLo, pZ,
            30, 0, 1, 0,
            mHi + 2L*262144, mLo + 2L*262144, 262144L,
            biasM + 1024, 512L,
            nullptr, 0L, 0,
            latHi, latLo, pZ);
        head_pi<<<dim3(CR/16), dim3(256), 0, stream>>>(
            latHi, latLo, actor_w, actor_b, out, t0);
        head_vf<<<dim3(CR/32), dim3(256), 0, stream>>>(
            latHi + pZ, latLo + pZ, critic_w, critic_b, out, t0);
    }
}

// Round 6
// 7188.015 us; speedup vs baseline: 3.8342x; 2.3428x over previous
//
#include <hip/hip_runtime.h>
#include <math.h>

#define BB 128
#define TT 512
#define DD 512
#define HH 512
#define NN (BB*TT)   // 65536
#define PP 512
#define AA 32
#define CH 64        // timesteps per chunk
#define CR (BB*CH)   // rows per chunk per net = 8192

typedef unsigned short u16;
typedef unsigned int   u32;
typedef __attribute__((ext_vector_type(8))) short short8;
typedef __attribute__((ext_vector_type(4))) float f32x4;

__device__ __forceinline__ u16 f2bf(float f){
    u32 x = __float_as_uint(f);
    u32 r = (x + 0x7fffu + ((x >> 16) & 1u)) >> 16;   // RNE
    return (u16)r;
}
__device__ __forceinline__ float bf2f(u16 u){
    return __uint_as_float(((u32)u) << 16);
}
__device__ __forceinline__ f32x4 mfma16(short8 a, short8 b, f32x4 c){
    return __builtin_amdgcn_mfma_f32_16x16x32_bf16(a, b, c, 0, 0, 0);
}
__device__ __forceinline__ float sigm(float x){
    return 1.f/(1.f + __expf(-x));
}
__device__ __forceinline__ float tanh_f(float x){
    return 1.f - 2.f/(1.f + __expf(2.f*x));
}

// sc0 load: bypass the per-CU L1 (post-barrier h reads must not hit stale L1;
// only L2 is refreshed by the leader's fence). Untracked by compiler vmcnt
// bookkeeping -> caller does explicit s_waitcnt (retire is in issue order).
__device__ __forceinline__ short8 ld_sc0(const u16* p){
    short8 r;
    asm volatile("global_load_dwordx4 %0, %1, off sc0"
                 : "=&v"(r) : "v"(p) : "memory");
    return r;
}

__device__ __forceinline__ unsigned a_add(unsigned* p){
    return __hip_atomic_fetch_add(p, 1u, __ATOMIC_RELAXED, __HIP_MEMORY_SCOPE_AGENT);
}
__device__ __forceinline__ unsigned a_ld(unsigned* p){
    return __hip_atomic_load(p, __ATOMIC_RELAXED, __HIP_MEMORY_SCOPE_AGENT);
}

// barZ layout (u32 indices), all counters 64B-padded:
//   ARR(t,x)  = (t*8+x)*16            [0,      65536)
//   DONE(t)   = 65536 + t*16          [65536,  73728)
//   RCNT(c,x) = 73728 + (c*8+x)*16    [73728,  74752)
//   SBAR(c)   = 74752 + c*16          [74752,  74880)
//   XCNT(c)   = 74880 + c*16          [74880,  75008)
#define BARZ_N 75264

// ---------------------------------------------------------------------------
// prep: permute+split LSTM weights. Both Wih and Whh PERMUTED: col c=u*4+g
// <- src row g*512+u. biasP permuted bih+bhh.
// ---------------------------------------------------------------------------
__global__ __launch_bounds__(256) void prep_lstm_w(
    const float* __restrict__ Wih_pi, const float* __restrict__ Whh_pi,
    const float* __restrict__ bih_pi, const float* __restrict__ bhh_pi,
    const float* __restrict__ Wih_vf, const float* __restrict__ Whh_vf,
    const float* __restrict__ bih_vf, const float* __restrict__ bhh_vf,
    u16* __restrict__ wihHi, u16* __restrict__ wihLo,
    u16* __restrict__ whhHi, u16* __restrict__ whhLo,
    float* __restrict__ biasP)
{
    long i = (long)blockIdx.x*256 + threadIdx.x;
    if (i >= 2L*2048*512) return;
    int L = (int)(i >> 20);
    int rem = (int)(i & 1048575);
    int c = rem >> 9, k = rem & 511;
    int u = c >> 2, g = c & 3;
    long src = (long)(g*512 + u)*512 + k;
    float wih = (L ? Wih_vf : Wih_pi)[src];
    float whh = (L ? Whh_vf : Whh_pi)[src];
    u16 h1 = f2bf(wih); wihHi[i] = h1; wihLo[i] = f2bf(wih - bf2f(h1));
    u16 h2 = f2bf(whh); whhHi[i] = h2; whhLo[i] = f2bf(whh - bf2f(h2));
    if (k == 0) {
        float b = (L ? bih_vf : bih_pi)[g*512+u] + (L ? bhh_vf : bhh_pi)[g*512+u];
        biasP[L*2048 + c] = b;
    }
}

// prep MLP weight planes: mat 0=w1pi 1=w1vf 2=w2pi 3=w2vf
__global__ __launch_bounds__(256) void prep_mlp_w(
    const float* __restrict__ w1pi, const float* __restrict__ w1vf,
    const float* __restrict__ w2pi, const float* __restrict__ w2vf,
    const float* __restrict__ b1pi, const float* __restrict__ b1vf,
    const float* __restrict__ b2pi, const float* __restrict__ b2vf,
    u16* __restrict__ mHi, u16* __restrict__ mLo, float* __restrict__ biasM)
{
    long i = (long)blockIdx.x*256 + threadIdx.x;
    if (i >= 4L*262144) return;
    int mat = (int)(i >> 18);
    int rem = (int)(i & 262143);
    const float* src = mat==0 ? w1pi : mat==1 ? w1vf : mat==2 ? w2pi : w2vf;
    float v = src[rem];
    u16 h = f2bf(v); mHi[i] = h; mLo[i] = f2bf(v - bf2f(h));
    if (rem < 512) {
        const float* bs = mat==0 ? b1pi : mat==1 ? b1vf : mat==2 ? b2pi : b2vf;
        biasM[mat*512 + rem] = bs[rem];
    }
}

// init: h planes [L][p=0][e][u] pre-masked; cT transposed [L][u][e] pre-masked;
// startsT [t][e]; zero ALL barrier/rank counters (fresh every graph replay).
__global__ __launch_bounds__(256) void init_state_k(
    const float* __restrict__ h0_pi, const float* __restrict__ c0_pi,
    const float* __restrict__ h0_vf, const float* __restrict__ c0_vf,
    const float* __restrict__ starts,
    u16* __restrict__ hHi, u16* __restrict__ hLo, float* __restrict__ cT,
    float* __restrict__ startsT, unsigned* __restrict__ barZ)
{
    int i = blockIdx.x*256 + threadIdx.x;
    if (i < BARZ_N) barZ[i] = 0u;
    if (i < NN) {
        int e = i >> 9, t = i & 511;
        startsT[t*128 + e] = starts[i];
    }
    if (i >= 2*BB*HH) return;
    int L = i >> 16; int r = i & 65535;
    int e = r >> 9, u = r & 511;
    float m = 1.0f - starts[(long)e*TT];
    float h = (L ? h0_vf : h0_pi)[r] * m;
    float c = (L ? c0_vf : c0_pi)[r] * m;
    long hidx = (long)(L*2)*65536 + r;    // [L][parity=0][e][u]
    u16 hh = f2bf(h);
    hHi[hidx] = hh; hLo[hidx] = f2bf(h - bf2f(hh));
    cT[(long)L*65536 + (long)u*128 + e] = c;
}

// ---------------------------------------------------------------------------
// generic K=512 split-bf16 GEMM, tile 128x128, 256 threads (4 waves, 64x64)
// AM: 0 = A fp32 (converted in staging)   1 = A hi/lo planes
// row map: arow = (m>>rowSh)*rowOuterHi + (m&mask)*rowOuterLo + rowBase
// EM: 0 = +bias -> fp32 out   1 = +bias,relu -> planes   2 = +bias -> planes
// ---------------------------------------------------------------------------
template<int AM, int EM>
__global__ __launch_bounds__(256) void gemm_k512(
    const float* __restrict__ Afp,
    const u16* __restrict__ aHi, const u16* __restrict__ aLo, long aZ,
    int rowSh, int rowOuterHi, int rowOuterLo, int rowBase,
    const u16* __restrict__ bHi, const u16* __restrict__ bLo, long bZ,
    const float* __restrict__ bias, long biasZ,
    float* __restrict__ outF, long outFZ, int outLd,
    u16* __restrict__ oHi, u16* __restrict__ oLo, long oZ)
{
    __shared__ u16 sAh[5120], sAl[5120], sBh[5120], sBl[5120];  // 128 x 40 each
    const int tid = threadIdx.x;
    const int z = blockIdx.z;
    const long Mbase = (long)blockIdx.x * 128;
    const long Nbase = (long)blockIdx.y * 128;
    const int r2 = tid >> 1, half = tid & 1;
    const long mstage = Mbase + r2;
    const long arow = (mstage >> rowSh) * (long)rowOuterHi
                    + (mstage & (((long)1<<rowSh)-1)) * (long)rowOuterLo + rowBase;
    const long brow = Nbase + r2;
    const int wid = tid >> 6, lane = tid & 63;
    const int mh = wid & 1, nh = wid >> 1;
    const int l15 = lane & 15, quad = lane >> 4;

    f32x4 acc[4][4];
    #pragma unroll
    for (int i = 0; i < 4; ++i)
        #pragma unroll
        for (int j = 0; j < 4; ++j)
            acc[i][j] = (f32x4){0.f,0.f,0.f,0.f};

    const int sOffW = r2*40 + half*16;

    for (int kt = 0; kt < 16; ++kt) {
        const int k0 = kt*32;
        if constexpr (AM == 0) {
            const float* ap = Afp + arow*512 + k0 + half*16;
            float fv[16];
            #pragma unroll
            for (int q = 0; q < 4; ++q) *(float4*)(fv + q*4) = ((const float4*)ap)[q];
            short8 vh0, vh1, vl0, vl1;
            #pragma unroll
            for (int i = 0; i < 8; ++i){
                u16 h  = f2bf(fv[i]);   vh0[i] = (short)h;  vl0[i] = (short)f2bf(fv[i]   - bf2f(h));
                u16 h2 = f2bf(fv[8+i]); vh1[i] = (short)h2; vl1[i] = (short)f2bf(fv[8+i] - bf2f(h2));
            }
            *(short8*)(sAh + sOffW) = vh0; *(short8*)(sAh + sOffW + 8) = vh1;
            *(short8*)(sAl + sOffW) = vl0; *(short8*)(sAl + sOffW + 8) = vl1;
        } else {
            const u16* ph = aHi + (long)z*aZ + arow*512 + k0 + half*16;
            const u16* pl = aLo + (long)z*aZ + arow*512 + k0 + half*16;
            *(short8*)(sAh + sOffW) = *(const short8*)ph;
            *(short8*)(sAh + sOffW + 8) = *(const short8*)(ph + 8);
            *(short8*)(sAl + sOffW) = *(const short8*)pl;
            *(short8*)(sAl + sOffW + 8) = *(const short8*)(pl + 8);
        }
        {
            const u16* ph = bHi + (long)z*bZ + brow*512 + k0 + half*16;
            const u16* pl = bLo + (long)z*bZ + brow*512 + k0 + half*16;
            *(short8*)(sBh + sOffW) = *(const short8*)ph;
            *(short8*)(sBh + sOffW + 8) = *(const short8*)(ph + 8);
            *(short8*)(sBl + sOffW) = *(const short8*)pl;
            *(short8*)(sBl + sOffW + 8) = *(const short8*)(pl + 8);
        }
        __syncthreads();
        short8 bh[4], bl[4];
        #pragma unroll
        for (int nt = 0; nt < 4; ++nt){
            int bo = (nh*64 + nt*16 + l15)*40 + quad*8;
            bh[nt] = *(const short8*)(sBh + bo);
            bl[nt] = *(const short8*)(sBl + bo);
        }
        #pragma unroll
        for (int mt = 0; mt < 4; ++mt){
            int ao = (mh*64 + mt*16 + l15)*40 + quad*8;
            short8 ah = *(const short8*)(sAh + ao);
            short8 al = *(const short8*)(sAl + ao);
            #pragma unroll
            for (int nt = 0; nt < 4; ++nt){
                acc[mt][nt] = mfma16(ah, bh[nt], acc[mt][nt]);
                acc[mt][nt] = mfma16(ah, bl[nt], acc[mt][nt]);
                acc[mt][nt] = mfma16(al, bh[nt], acc[mt][nt]);
            }
        }
        __syncthreads();
    }
    #pragma unroll
    for (int nt = 0; nt < 4; ++nt){
        const long col = Nbase + nh*64 + nt*16 + l15;
        const float bv = bias[(long)z*biasZ + col];
        #pragma unroll
        for (int mt = 0; mt < 4; ++mt){
            const long rowm = Mbase + mh*64 + mt*16 + quad*4;
            #pragma unroll
            for (int rr = 0; rr < 4; ++rr){
                float v = acc[mt][nt][rr] + bv;
                const long m = rowm + rr;
                if constexpr (EM == 0) {
                    outF[(long)z*outFZ + m*(long)outLd + col] = v;
                } else {
                    if constexpr (EM == 1) v = fmaxf(v, 0.f);
                    u16 h = f2bf(v);
                    u16 l = f2bf(v - bf2f(h));
                    oHi[(long)z*oZ + m*512 + col] = h;
                    oLo[(long)z*oZ + m*512 + col] = l;
                }
            }
        }
    }
}

// ---------------------------------------------------------------------------
// Persistent LSTM chunk (round-4 geometry, which ran CORRECTLY): 64 steps,
// ONE plain launch, grid (64 wc, 2 eb, 2 L) = 256 blocks x 256 threads,
// 68KB LDS -> 2 blocks/CU residency margin (no round-5 deadlock exposure).
// Whh staged to LDS once per chunk; cT in registers; h stores plain/cached.
//
// Barrier = round-4 semantics at 1/32 the fence cost: blocks arrive at a
// per-XCD counter; ONE leader per XCD (runtime-elected; per-XCD block count
// DISCOVERED, not assumed) executes the single __threadfence() -- wbl2/inv
// are whole-cache ops, so one per XCD flushes every co-located writer's
// stores (each drained vmcnt(0) pre-arrival). All blocks then spin a global
// done[t] == xcdCount gate, so reads start only after every XCD's writeback.
// h loads use sc0 (L1 bypass) since leader fences don't touch other CUs' L1.
// Arithmetic identical to round 4 (bit-identical results).
// ---------------------------------------------------------------------------
__global__ __launch_bounds__(256) void lstm_chunk(
    u16* __restrict__ hHi, u16* __restrict__ hLo,           // [L][2][128][512]
    const u16* __restrict__ whhHi, const u16* __restrict__ whhLo, // [L][2048][512] permuted
    const float* __restrict__ gx,                            // [L][tau][128][2048]
    const float* __restrict__ startsT,                       // [t][128]
    float* __restrict__ cT,                                  // [L][512][128]
    u16* __restrict__ ysHi, u16* __restrict__ ysLo,          // [L][tau][128][512]
    float* __restrict__ dout, unsigned* __restrict__ barZ, int t0)
{
    __shared__ __attribute__((aligned(16))) u16 sA[2][16384];  // [plane][kt][wcol][32k]
    __shared__ float zsm[4][144];
    __shared__ unsigned shLead, shNloc, shXC;

    const int tid  = threadIdx.x;
    const int wc   = blockIdx.x;         // 0..63 : 32 gate-cols
    const int eb   = blockIdx.y;         // 0..1  : 64-env half
    const int L    = blockIdx.z;
    const int wid  = tid >> 6, lane = tid & 63;
    const int l15  = lane & 15, quad = lane >> 4;
    const int ebase = eb*64;
    const int e    = ebase + wid*16 + l15;       // this lane's env (as B row)

    unsigned xcc;
    asm("s_getreg_b32 %0, hwreg(HW_REG_XCC_ID)" : "=s"(xcc));
    xcc &= 7u;
    const int ch = t0 >> 6;
    unsigned* ARRb  = barZ;
    unsigned* DONEb = barZ + 65536;
    unsigned* RCNTb = barZ + 73728;
    unsigned* SBARb = barZ + 74752;
    unsigned* XCNTb = barZ + 74880;

    // ---- leader election + per-XCD census (once per chunk). XCNT add is
    // drained (vmcnt 0) before SBAR arrive so SBAR==256 => all XCNT adds done.
    if (tid == 0){
        unsigned r = a_add(&RCNTb[(ch*8 + (int)xcc)*16]);
        shLead = (r == 0u) ? 1u : 0u;
        if (r == 0u){
            a_add(&XCNTb[ch*16]);
            asm volatile("s_waitcnt vmcnt(0)" ::: "memory");
        }
        a_add(&SBARb[ch*16]);
        while (a_ld(&SBARb[ch*16]) < 256u) __builtin_amdgcn_s_sleep(2);
        shNloc = a_ld(&RCNTb[(ch*8 + (int)xcc)*16]);
        shXC   = a_ld(&XCNTb[ch*16]);
    }

    // ---- stage Whh' panel ONCE: 32 wcols x 512 k x hi/lo = 64 KB
    {
        const size_t wbase = (size_t)L*1048576 + (size_t)(wc*32)*512;
        #pragma unroll
        for (int i = 0; i < 16; ++i){
            int f = tid + i*256;          // 0..4095
            int pl = f >> 11;
            int r2 = f & 2047;
            int wcol = r2 >> 6, ksg = r2 & 63;
            const u16* src = (pl ? whhLo : whhHi) + wbase + (size_t)wcol*512 + ksg*8;
            int dst = (ksg>>2)*1024 + wcol*32 + (ksg&3)*8;
            *(short8*)(sA[pl] + dst) = *(const short8*)src;
        }
    }
    __syncthreads();
    const unsigned lead = shLead, nloc = shNloc, xcnt = shXC;

    // ---- cT in registers for the whole chunk (block-stationary ownership)
    const int u0 = wc*8 + quad;          // mt=0 unit
    const int u1 = wc*8 + 4 + quad;      // mt=1 unit
    const size_t ci0 = (size_t)L*65536 + (size_t)u0*128 + e;
    const size_t ci1 = (size_t)L*65536 + (size_t)u1*128 + e;
    float c0 = cT[ci0];
    float c1 = cT[ci1];

    const size_t hrowOff = (size_t)e*512 + quad*8;
    const size_t gxbase  = ((size_t)L*CR + e)*2048 + wc*32 + quad*4;

    for (int tau = 0; tau < CH; ++tau){
        const int t = t0 + tau;
        const int p = t & 1;

        // gx (HBM) + mask loads issue first; latency hides under the K-loop
        const float* gp = gx + gxbase + (size_t)tau*(128*2048);
        float4 gv0 = *(const float4*)(gp);
        float4 gv1 = *(const float4*)(gp + 16);
        const float mn = (t < TT-1) ? (1.0f - startsT[(t+1)*128 + e]) : 1.0f;

        // ---- K loop, 4-deep pipelined sc0 h-loads (L1 bypass; L2 fresh via
        // leader fences). vmcnt retires in issue order: waiting to <=6
        // outstanding always retires the consumed pair, regardless of where
        // the compiler placed its own (earlier-issued) gx/mask loads.
        const u16* hHiP = hHi + (size_t)(L*2+p)*65536 + hrowOff;
        const u16* hLoP = hLo + (size_t)(L*2+p)*65536 + hrowOff;
        short8 pbh[4], pbl[4];
        #pragma unroll
        for (int i = 0; i < 4; ++i){
            pbh[i] = ld_sc0(hHiP + i*32);
            pbl[i] = ld_sc0(hLoP + i*32);
        }
        f32x4 acc0 = (f32x4){0.f,0.f,0.f,0.f};
        f32x4 acc1 = (f32x4){0.f,0.f,0.f,0.f};
        #pragma unroll
        for (int kt = 0; kt < 16; ++kt){
            if (kt < 13)      asm volatile("s_waitcnt vmcnt(6)" ::: "memory");
            else if (kt==13)  asm volatile("s_waitcnt vmcnt(4)" ::: "memory");
            else if (kt==14)  asm volatile("s_waitcnt vmcnt(2)" ::: "memory");
            else              asm volatile("s_waitcnt vmcnt(0)" ::: "memory");
            __builtin_amdgcn_sched_barrier(0);
            short8 bh = pbh[kt & 3];
            short8 bl = pbl[kt & 3];
            int a0 = kt*1024 + l15*32 + quad*8;          // mt=0 rows l15, mt=1 rows 16+l15
            short8 ah0 = *(const short8*)(sA[0] + a0);
            short8 al0 = *(const short8*)(sA[1] + a0);
            short8 ah1 = *(const short8*)(sA[0] + a0 + 512);
            short8 al1 = *(const short8*)(sA[1] + a0 + 512);
            acc0 = mfma16(ah0, bh, acc0);
            acc0 = mfma16(ah0, bl, acc0);
            acc0 = mfma16(al0, bh, acc0);
            acc1 = mfma16(ah1, bh, acc1);
            acc1 = mfma16(ah1, bl, acc1);
            acc1 = mfma16(al1, bh, acc1);
            if (kt < 12){
                pbh[kt & 3] = ld_sc0(hHiP + (kt+4)*32);
                pbl[kt & 3] = ld_sc0(hLoP + (kt+4)*32);
            }
        }

        // ---- gates -> state update (env = l15, unit = quad, gates = regs)
        {
            float ii = sigm(acc0[0] + gv0.x);
            float ff = sigm(acc0[1] + gv0.y);
            float gg = tanh_f(acc0[2] + gv0.z);
            float oo = sigm(acc0[3] + gv0.w);
            float cn = ff*c0 + ii*gg;
            float hn = oo * tanh_f(cn);
            c0 = cn * mn;
            zsm[wid][l15*8 + quad] = hn;
            zsm[wid][128 + l15] = mn;
            if (t == TT-1) {
                dout[(size_t)(3+2*L)*NN + (size_t)e*512 + u0] = hn;
                dout[(size_t)(4+2*L)*NN + (size_t)e*512 + u0] = cn;
            }
        }
        {
            float ii = sigm(acc1[0] + gv1.x);
            float ff = sigm(acc1[1] + gv1.y);
            float gg = tanh_f(acc1[2] + gv1.z);
            float oo = sigm(acc1[3] + gv1.w);
            float cn = ff*c1 + ii*gg;
            float hn = oo * tanh_f(cn);
            c1 = cn * mn;
            zsm[wid][l15*8 + 4 + quad] = hn;
            if (t == TT-1) {
                dout[(size_t)(3+2*L)*NN + (size_t)e*512 + u1] = hn;
                dout[(size_t)(4+2*L)*NN + (size_t)e*512 + u1] = cn;
            }
        }
        __syncthreads();

        // ---- coalesced h / ys writes: role = quad (0:hHi 1:hLo 2:ysHi 3:ysLo)
        {
            const int role = quad;
            const int e2 = l15;
            const int eg = ebase + wid*16 + e2;
            float v[8];
            #pragma unroll
            for (int j = 0; j < 8; ++j) v[j] = zsm[wid][e2*8 + j];
            const float mn2 = zsm[wid][128 + e2];
            short8 pk;
            if (role < 2) {
                #pragma unroll
                for (int j = 0; j < 8; ++j){
                    float hm = v[j] * mn2;
                    u16 h = f2bf(hm);
                    pk[j] = (short)(role == 0 ? h : f2bf(hm - bf2f(h)));
                }
                u16* dst = (role == 0 ? hHi : hLo)
                         + (size_t)(L*2 + (1-p))*65536 + (size_t)eg*512 + wc*8;
                *(short8*)dst = pk;
            } else {
                #pragma unroll
                for (int j = 0; j < 8; ++j){
                    u16 h = f2bf(v[j]);
                    pk[j] = (short)(role == 2 ? h : f2bf(v[j] - bf2f(h)));
                }
                u16* dst = (role == 2 ? ysHi : ysLo)
                         + ((size_t)L*CR + (size_t)tau*128 + eg)*512 + wc*8;
                *(short8*)dst = pk;
            }
        }

        // ---- device barrier, leader-fence edition (skip after last step:
        // the kernel boundary orders the hand-off to the MLP GEMMs)
        if (tau < CH-1){
            asm volatile("s_waitcnt vmcnt(0)" ::: "memory");  // stores in my L2
            __syncthreads();
            if (tid == 0){
                unsigned* ap = &ARRb[((size_t)t*8 + xcc)*16];
                unsigned* dp = &DONEb[(size_t)t*16];
                a_add(ap);
                if (lead){
                    while (a_ld(ap) < nloc) __builtin_amdgcn_s_sleep(1);
                    __threadfence();                 // ONE wbl2+inv per XCD
                    a_add(dp);
                }
                while (a_ld(dp) < xcnt) __builtin_amdgcn_s_sleep(1);
            }
            __syncthreads();
            asm volatile("" ::: "memory");
        }
    }

    cT[ci0] = c0;
    cT[ci1] = c1;
}

// ---------------------------------------------------------------------------
// heads: chunk row m = tau*128 + e  ->  n = e*TT + t0 + tau
// ---------------------------------------------------------------------------
__global__ __launch_bounds__(256) void head_pi(
    const u16* __restrict__ latHi, const u16* __restrict__ latLo,
    const float* __restrict__ actor_w, const float* __restrict__ actor_b,
    float* __restrict__ dout, int t0)
{
    __shared__ float latS[16*516];
    __shared__ float lg[16*36];
    const int tid = threadIdx.x;
    const long r0 = (long)blockIdx.x * 16;
    {
        int rr = tid >> 4, seg = tid & 15;
        const u16* ph = latHi + (r0 + rr)*512 + seg*32;
        const u16* pl = latLo + (r0 + rr)*512 + seg*32;
        float* dst = latS + rr*516 + seg*32;
        #pragma unroll
        for (int ii = 0; ii < 4; ++ii){
            short8 vh = *(const short8*)(ph + ii*8);
            short8 vl = *(const short8*)(pl + ii*8);
            #pragma unroll
            for (int jj = 0; jj < 8; ++jj)
                dst[ii*8+jj] = bf2f((u16)vh[jj]) + bf2f((u16)vl[jj]);
        }
    }
    __syncthreads();
    {
        int rr = tid >> 4, a0 = (tid & 15)*2;
        const float4* lrow = (const float4*)(latS + rr*516);
        float acc0 = actor_b[a0], acc1 = actor_b[a0+1];
        for (int kq = 0; kq < 128; ++kq){
            float4 lv = lrow[kq];
            float4 w0 = ((const float4*)actor_w)[(a0  )*128 + kq];
            float4 w1 = ((const float4*)actor_w)[(a0+1)*128 + kq];
            acc0 += lv.x*w0.x + lv.y*w0.y + lv.z*w0.z + lv.w*w0.w;
            acc1 += lv.x*w1.x + lv.y*w1.y + lv.z*w1.z + lv.w*w1.w;
        }
        lg[rr*36 + a0]   = acc0;
        lg[rr*36 + a0+1] = acc1;
    }
    __syncthreads();
    if (tid < 16){
        float mx = -INFINITY; int am = 0;
        #pragma unroll
        for (int a = 0; a < AA; ++a){
            float v = lg[tid*36 + a];
            if (v > mx){ mx = v; am = a; }
        }
        float se = 0.f;
        #pragma unroll
        for (int a = 0; a < AA; ++a) se += expf(lg[tid*36 + a] - mx);
        long row = r0 + tid;
        long n = (row & 127)*TT + t0 + (row >> 7);
        dout[n] = (float)am;
        dout[2L*NN + n] = -logf(se);
    }
}

__global__ __launch_bounds__(256) void head_vf(
    const u16* __restrict__ latHi, const u16* __restrict__ latLo,
    const float* __restrict__ critic_w, const float* __restrict__ critic_b,
    float* __restrict__ dout, int t0)
{
    __shared__ float part[256];
    const int tid = threadIdx.x;
    const long r0 = (long)blockIdx.x * 32;
    int rr = tid >> 3, seg = tid & 7;
    const u16* ph = latHi + (r0 + rr)*512 + seg*64;
    const u16* pl = latLo + (r0 + rr)*512 + seg*64;
    float acc = 0.f;
    #pragma unroll
    for (int ii = 0; ii < 8; ++ii){
        short8 vh = *(const short8*)(ph + ii*8);
        short8 vl = *(const short8*)(pl + ii*8);
        #pragma unroll
        for (int jj = 0; jj < 8; ++jj){
            float lv = bf2f((u16)vh[jj]) + bf2f((u16)vl[jj]);
            acc += lv * critic_w[seg*64 + ii*8 + jj];
        }
    }
    part[tid] = acc;
    __syncthreads();
    if (tid < 32){
        float v = critic_b[0];
        #pragma unroll
        for (int s = 0; s < 8; ++s) v += part[tid*8 + s];
        long row = r0 + tid;
        long n = (row & 127)*TT + t0 + (row >> 7);
        dout[(long)NN + n] = v;
    }
}

// ---------------------------------------------------------------------------
extern "C" void kernel_launch(void* const* d_in, const int* in_sizes, int n_in,
                              void* d_out, int out_size, void* d_ws, size_t ws_size,
                              hipStream_t stream) {
    const float* features = (const float*)d_in[0];
    const float* starts   = (const float*)d_in[1];
    const float* h0_pi = (const float*)d_in[2];
    const float* c0_pi = (const float*)d_in[3];
    const float* h0_vf = (const float*)d_in[4];
    const float* c0_vf = (const float*)d_in[5];
    const float* Wih_pi = (const float*)d_in[6];
    const float* Whh_pi = (const float*)d_in[7];
    const float* bih_pi = (const float*)d_in[8];
    const float* bhh_pi = (const float*)d_in[9];
    const float* Wih_vf = (const float*)d_in[10];
    const float* Whh_vf = (const float*)d_in[11];
    const float* bih_vf = (const float*)d_in[12];
    const float* bhh_vf = (const float*)d_in[13];
    const float* pol_w1 = (const float*)d_in[14];
    const float* pol_b1 = (const float*)d_in[15];
    const float* pol_w2 = (const float*)d_in[16];
    const float* pol_b2 = (const float*)d_in[17];
    const float* val_w1 = (const float*)d_in[18];
    const float* val_b1 = (const float*)d_in[19];
    const float* val_w2 = (const float*)d_in[20];
    const float* val_b2 = (const float*)d_in[21];
    const float* actor_w  = (const float*)d_in[22];
    const float* actor_b  = (const float*)d_in[23];
    const float* critic_w = (const float*)d_in[24];
    const float* critic_b = (const float*)d_in[25];
    float* out = (float*)d_out;

    size_t off = 0;
    auto alloc = [&](size_t b) {
        void* p = (char*)d_ws + off;
        off += (b + 255) & ~(size_t)255;
        return p;
    };
    u16* wihHi = (u16*)alloc(2L*2048*512*2);
    u16* wihLo = (u16*)alloc(2L*2048*512*2);
    u16* whhHi = (u16*)alloc(2L*2048*512*2);
    u16* whhLo = (u16*)alloc(2L*2048*512*2);
    float* biasP = (float*)alloc(2L*2048*4);
    u16* mHi = (u16*)alloc(4L*262144*2);
    u16* mLo = (u16*)alloc(4L*262144*2);
    float* biasM = (float*)alloc(4L*512*4);
    u16* hHi = (u16*)alloc(2L*2*128*512*2);
    u16* hLo = (u16*)alloc(2L*2*128*512*2);
    float* cT  = (float*)alloc(2L*128*512*4);
    float* startsT = (float*)alloc((size_t)NN*4);
    unsigned* barZ = (unsigned*)alloc((size_t)BARZ_N*4);
    u16* ysHi = (u16*)alloc(2L*CR*512*2);
    u16* ysLo = (u16*)alloc(2L*CR*512*2);
    u16* hidHi = (u16*)alloc(2L*CR*512*2);
    u16* hidLo = (u16*)alloc(2L*CR*512*2);
    u16* latHi = (u16*)alloc(2L*CR*512*2);
    u16* latLo = (u16*)alloc(2L*CR*512*2);
    float* gxF = (float*)alloc(2L*CR*2048*4);     // [L][tau][128][2048], 134 MB
    const long gxZ = (long)CR*2048;               // per-net stride
    const long pZ  = (long)CR*512;                // plane per-net stride

    prep_lstm_w<<<dim3(8192), dim3(256), 0, stream>>>(
        Wih_pi, Whh_pi, bih_pi, bhh_pi, Wih_vf, Whh_vf, bih_vf, bhh_vf,
        wihHi, wihLo, whhHi, whhLo, biasP);
    prep_mlp_w<<<dim3(4096), dim3(256), 0, stream>>>(
        pol_w1, val_w1, pol_w2, val_w2, pol_b1, val_b1, pol_b2, val_b2,
        mHi, mLo, biasM);
    init_state_k<<<dim3(512), dim3(256), 0, stream>>>(
        h0_pi, c0_pi, h0_vf, c0_vf, starts, hHi, hLo, cT, startsT, barZ);

    for (int t0 = 0; t0 < TT; t0 += CH) {
        // gx[L][tau][e][2048] = x @ Wih'^T + (bih+bhh); out row m = tau*128+e,
        // feature row = e*512 + t0 + tau  -> arow = (m&127)*512 + (m>>7) + t0
        gemm_k512<0,0><<<dim3(CR/128, 16, 2), dim3(256), 0, stream>>>(
            features, nullptr, nullptr, 0L,
            7, 1, 512, t0,
            wihHi, wihLo, 1048576L,
            biasP, 2048L,
            gxF, gxZ, 2048,
            nullptr, nullptr, 0L);
        // 64 recurrent steps in ONE persistent plain launch (leader-fence sync)
        lstm_chunk<<<dim3(64, 2, 2), dim3(256), 0, stream>>>(
            hHi, hLo, whhHi, whhLo, gxF, startsT, cT, ysHi, ysLo,
            out, barZ, t0);
        // MLP layers on the chunk (rows = tau*128+e, identity map)
        gemm_k512<1,1><<<dim3(CR/128, 4, 2), dim3(256), 0, stream>>>(
            nullptr, ysHi, ysLo, pZ,
            30, 0, 1, 0,
            mHi, mLo, 262144L,
            biasM, 512L,
            nullptr, 0L, 0,
            hidHi, hidLo, pZ);
        gemm_k512<1,2><<<dim3(CR/128, 4, 2), dim3(256), 0, stream>>>(
            nullptr, hidHi, hidLo, pZ,
            30, 0, 1, 0,
            mHi + 2L*262144, mLo + 2L*262144, 262144L,
            biasM + 1024, 512L,
            nullptr, 0L, 0,
            latHi, latLo, pZ);
        head_pi<<<dim3(CR/16), dim3(256), 0, stream>>>(
            latHi, latLo, actor_w, actor_b, out, t0);
        head_vf<<<dim3(CR/32), dim3(256), 0, stream>>>(
            latHi + pZ, latLo + pZ, critic_w, critic_b, out, t0);
    }
}

// Round 7
// 6815.957 us; speedup vs baseline: 4.0435x; 1.0546x over previous
//
#include <hip/hip_runtime.h>
#include <math.h>

#define BB 128
#define TT 512
#define DD 512
#define HH 512
#define NN (BB*TT)   // 65536
#define PP 512
#define AA 32
#define CH 64        // timesteps per chunk
#define CR (BB*CH)   // rows per chunk per net = 8192

typedef unsigned short u16;
typedef unsigned int   u32;
typedef __attribute__((ext_vector_type(8))) short short8;
typedef __attribute__((ext_vector_type(4))) float f32x4;

__device__ __forceinline__ u16 f2bf(float f){
    u32 x = __float_as_uint(f);
    u32 r = (x + 0x7fffu + ((x >> 16) & 1u)) >> 16;   // RNE
    return (u16)r;
}
__device__ __forceinline__ float bf2f(u16 u){
    return __uint_as_float(((u32)u) << 16);
}
__device__ __forceinline__ f32x4 mfma16(short8 a, short8 b, f32x4 c){
    return __builtin_amdgcn_mfma_f32_16x16x32_bf16(a, b, c, 0, 0, 0);
}
__device__ __forceinline__ float sigm(float x){
    return 1.f/(1.f + __expf(-x));
}
__device__ __forceinline__ float tanh_f(float x){
    return 1.f - 2.f/(1.f + __expf(2.f*x));
}

// MALL-coherent h path: sc0 (L1 bypass/no-alloc) + sc1 (L2 bypass/no-alloc).
// Loads read the coherence point; stores write through to it. Since h lines
// are NEVER allocated in any L1/L2 (both directions no-alloc, and caches are
// invalidated at dispatch start), there is no stale-hit path -- so the step
// barrier needs NO wbl2/inv at all: vmcnt(0) == release (stores acked at
// MALL before the arrive-RMW issues). This removes round 6's per-step
// leader __threadfence (the remaining 8 whole-L2 wb+inv per step) AND stops
// invalidating the gx stream out of L2 every step.
// NOTE: untracked by compiler vmcnt bookkeeping -> explicit s_waitcnt.
__device__ __forceinline__ short8 ld_mall(const u16* p){
    short8 r;
    asm volatile("global_load_dwordx4 %0, %1, off sc0 sc1"
                 : "=&v"(r) : "v"(p) : "memory");
    return r;
}
__device__ __forceinline__ void st_mall(u16* p, short8 v){
    asm volatile("global_store_dwordx4 %0, %1, off sc0 sc1"
                 :: "v"(p), "v"(v) : "memory");
}

__device__ __forceinline__ unsigned a_add(unsigned* p){
    return __hip_atomic_fetch_add(p, 1u, __ATOMIC_RELAXED, __HIP_MEMORY_SCOPE_AGENT);
}
__device__ __forceinline__ unsigned a_ld(unsigned* p){
    return __hip_atomic_load(p, __ATOMIC_RELAXED, __HIP_MEMORY_SCOPE_AGENT);
}

// barZ layout (u32 indices), all counters 64B-padded:
//   ARR(t,x)  = (t*8+x)*16            [0,      65536)
//   DONE(t)   = 65536 + t*16          [65536,  73728)
//   RCNT(c,x) = 73728 + (c*8+x)*16    [73728,  74752)
//   SBAR(c)   = 74752 + c*16          [74752,  74880)
//   XCNT(c)   = 74880 + c*16          [74880,  75008)
#define BARZ_N 75264

// ---------------------------------------------------------------------------
// prep: permute+split LSTM weights. Both Wih and Whh PERMUTED: col c=u*4+g
// <- src row g*512+u. biasP permuted bih+bhh.
// ---------------------------------------------------------------------------
__global__ __launch_bounds__(256) void prep_lstm_w(
    const float* __restrict__ Wih_pi, const float* __restrict__ Whh_pi,
    const float* __restrict__ bih_pi, const float* __restrict__ bhh_pi,
    const float* __restrict__ Wih_vf, const float* __restrict__ Whh_vf,
    const float* __restrict__ bih_vf, const float* __restrict__ bhh_vf,
    u16* __restrict__ wihHi, u16* __restrict__ wihLo,
    u16* __restrict__ whhHi, u16* __restrict__ whhLo,
    float* __restrict__ biasP)
{
    long i = (long)blockIdx.x*256 + threadIdx.x;
    if (i >= 2L*2048*512) return;
    int L = (int)(i >> 20);
    int rem = (int)(i & 1048575);
    int c = rem >> 9, k = rem & 511;
    int u = c >> 2, g = c & 3;
    long src = (long)(g*512 + u)*512 + k;
    float wih = (L ? Wih_vf : Wih_pi)[src];
    float whh = (L ? Whh_vf : Whh_pi)[src];
    u16 h1 = f2bf(wih); wihHi[i] = h1; wihLo[i] = f2bf(wih - bf2f(h1));
    u16 h2 = f2bf(whh); whhHi[i] = h2; whhLo[i] = f2bf(whh - bf2f(h2));
    if (k == 0) {
        float b = (L ? bih_vf : bih_pi)[g*512+u] + (L ? bhh_vf : bhh_pi)[g*512+u];
        biasP[L*2048 + c] = b;
    }
}

// prep MLP weight planes: mat 0=w1pi 1=w1vf 2=w2pi 3=w2vf
__global__ __launch_bounds__(256) void prep_mlp_w(
    const float* __restrict__ w1pi, const float* __restrict__ w1vf,
    const float* __restrict__ w2pi, const float* __restrict__ w2vf,
    const float* __restrict__ b1pi, const float* __restrict__ b1vf,
    const float* __restrict__ b2pi, const float* __restrict__ b2vf,
    u16* __restrict__ mHi, u16* __restrict__ mLo, float* __restrict__ biasM)
{
    long i = (long)blockIdx.x*256 + threadIdx.x;
    if (i >= 4L*262144) return;
    int mat = (int)(i >> 18);
    int rem = (int)(i & 262143);
    const float* src = mat==0 ? w1pi : mat==1 ? w1vf : mat==2 ? w2pi : w2vf;
    float v = src[rem];
    u16 h = f2bf(v); mHi[i] = h; mLo[i] = f2bf(v - bf2f(h));
    if (rem < 512) {
        const float* bs = mat==0 ? b1pi : mat==1 ? b1vf : mat==2 ? b2pi : b2vf;
        biasM[mat*512 + rem] = bs[rem];
    }
}

// init: h planes [L][p=0][e][u] pre-masked; cT transposed [L][u][e] pre-masked;
// startsT [t][e]; zero ALL barrier/rank counters (fresh every graph replay).
__global__ __launch_bounds__(256) void init_state_k(
    const float* __restrict__ h0_pi, const float* __restrict__ c0_pi,
    const float* __restrict__ h0_vf, const float* __restrict__ c0_vf,
    const float* __restrict__ starts,
    u16* __restrict__ hHi, u16* __restrict__ hLo, float* __restrict__ cT,
    float* __restrict__ startsT, unsigned* __restrict__ barZ)
{
    int i = blockIdx.x*256 + threadIdx.x;
    if (i < BARZ_N) barZ[i] = 0u;
    if (i < NN) {
        int e = i >> 9, t = i & 511;
        startsT[t*128 + e] = starts[i];
    }
    if (i >= 2*BB*HH) return;
    int L = i >> 16; int r = i & 65535;
    int e = r >> 9, u = r & 511;
    float m = 1.0f - starts[(long)e*TT];
    float h = (L ? h0_vf : h0_pi)[r] * m;
    float c = (L ? c0_vf : c0_pi)[r] * m;
    long hidx = (long)(L*2)*65536 + r;    // [L][parity=0][e][u]
    u16 hh = f2bf(h);
    hHi[hidx] = hh; hLo[hidx] = f2bf(h - bf2f(hh));
    cT[(long)L*65536 + (long)u*128 + e] = c;
}

// ---------------------------------------------------------------------------
// generic K=512 split-bf16 GEMM, tile 128x128, 256 threads (4 waves, 64x64)
// AM: 0 = A fp32 (converted in staging)   1 = A hi/lo planes
// row map: arow = (m>>rowSh)*rowOuterHi + (m&mask)*rowOuterLo + rowBase
// EM: 0 = +bias -> fp32 out   1 = +bias,relu -> planes   2 = +bias -> planes
// ---------------------------------------------------------------------------
template<int AM, int EM>
__global__ __launch_bounds__(256) void gemm_k512(
    const float* __restrict__ Afp,
    const u16* __restrict__ aHi, const u16* __restrict__ aLo, long aZ,
    int rowSh, int rowOuterHi, int rowOuterLo, int rowBase,
    const u16* __restrict__ bHi, const u16* __restrict__ bLo, long bZ,
    const float* __restrict__ bias, long biasZ,
    float* __restrict__ outF, long outFZ, int outLd,
    u16* __restrict__ oHi, u16* __restrict__ oLo, long oZ)
{
    __shared__ u16 sAh[5120], sAl[5120], sBh[5120], sBl[5120];  // 128 x 40 each
    const int tid = threadIdx.x;
    const int z = blockIdx.z;
    const long Mbase = (long)blockIdx.x * 128;
    const long Nbase = (long)blockIdx.y * 128;
    const int r2 = tid >> 1, half = tid & 1;
    const long mstage = Mbase + r2;
    const long arow = (mstage >> rowSh) * (long)rowOuterHi
                    + (mstage & (((long)1<<rowSh)-1)) * (long)rowOuterLo + rowBase;
    const long brow = Nbase + r2;
    const int wid = tid >> 6, lane = tid & 63;
    const int mh = wid & 1, nh = wid >> 1;
    const int l15 = lane & 15, quad = lane >> 4;

    f32x4 acc[4][4];
    #pragma unroll
    for (int i = 0; i < 4; ++i)
        #pragma unroll
        for (int j = 0; j < 4; ++j)
            acc[i][j] = (f32x4){0.f,0.f,0.f,0.f};

    const int sOffW = r2*40 + half*16;

    for (int kt = 0; kt < 16; ++kt) {
        const int k0 = kt*32;
        if constexpr (AM == 0) {
            const float* ap = Afp + arow*512 + k0 + half*16;
            float fv[16];
            #pragma unroll
            for (int q = 0; q < 4; ++q) *(float4*)(fv + q*4) = ((const float4*)ap)[q];
            short8 vh0, vh1, vl0, vl1;
            #pragma unroll
            for (int i = 0; i < 8; ++i){
                u16 h  = f2bf(fv[i]);   vh0[i] = (short)h;  vl0[i] = (short)f2bf(fv[i]   - bf2f(h));
                u16 h2 = f2bf(fv[8+i]); vh1[i] = (short)h2; vl1[i] = (short)f2bf(fv[8+i] - bf2f(h2));
            }
            *(short8*)(sAh + sOffW) = vh0; *(short8*)(sAh + sOffW + 8) = vh1;
            *(short8*)(sAl + sOffW) = vl0; *(short8*)(sAl + sOffW + 8) = vl1;
        } else {
            const u16* ph = aHi + (long)z*aZ + arow*512 + k0 + half*16;
            const u16* pl = aLo + (long)z*aZ + arow*512 + k0 + half*16;
            *(short8*)(sAh + sOffW) = *(const short8*)ph;
            *(short8*)(sAh + sOffW + 8) = *(const short8*)(ph + 8);
            *(short8*)(sAl + sOffW) = *(const short8*)pl;
            *(short8*)(sAl + sOffW + 8) = *(const short8*)(pl + 8);
        }
        {
            const u16* ph = bHi + (long)z*bZ + brow*512 + k0 + half*16;
            const u16* pl = bLo + (long)z*bZ + brow*512 + k0 + half*16;
            *(short8*)(sBh + sOffW) = *(const short8*)ph;
            *(short8*)(sBh + sOffW + 8) = *(const short8*)(ph + 8);
            *(short8*)(sBl + sOffW) = *(const short8*)pl;
            *(short8*)(sBl + sOffW + 8) = *(const short8*)(pl + 8);
        }
        __syncthreads();
        short8 bh[4], bl[4];
        #pragma unroll
        for (int nt = 0; nt < 4; ++nt){
            int bo = (nh*64 + nt*16 + l15)*40 + quad*8;
            bh[nt] = *(const short8*)(sBh + bo);
            bl[nt] = *(const short8*)(sBl + bo);
        }
        #pragma unroll
        for (int mt = 0; mt < 4; ++mt){
            int ao = (mh*64 + mt*16 + l15)*40 + quad*8;
            short8 ah = *(const short8*)(sAh + ao);
            short8 al = *(const short8*)(sAl + ao);
            #pragma unroll
            for (int nt = 0; nt < 4; ++nt){
                acc[mt][nt] = mfma16(ah, bh[nt], acc[mt][nt]);
                acc[mt][nt] = mfma16(ah, bl[nt], acc[mt][nt]);
                acc[mt][nt] = mfma16(al, bh[nt], acc[mt][nt]);
            }
        }
        __syncthreads();
    }
    #pragma unroll
    for (int nt = 0; nt < 4; ++nt){
        const long col = Nbase + nh*64 + nt*16 + l15;
        const float bv = bias[(long)z*biasZ + col];
        #pragma unroll
        for (int mt = 0; mt < 4; ++mt){
            const long rowm = Mbase + mh*64 + mt*16 + quad*4;
            #pragma unroll
            for (int rr = 0; rr < 4; ++rr){
                float v = acc[mt][nt][rr] + bv;
                const long m = rowm + rr;
                if constexpr (EM == 0) {
                    outF[(long)z*outFZ + m*(long)outLd + col] = v;
                } else {
                    if constexpr (EM == 1) v = fmaxf(v, 0.f);
                    u16 h = f2bf(v);
                    u16 l = f2bf(v - bf2f(h));
                    oHi[(long)z*oZ + m*512 + col] = h;
                    oLo[(long)z*oZ + m*512 + col] = l;
                }
            }
        }
    }
}

// ---------------------------------------------------------------------------
// Persistent LSTM chunk (round-6 base, VERIFIED): 64 steps, ONE plain launch,
// grid (64 wc, 2 eb, 2 L) = 256 blocks x 256 threads, 68KB LDS.
// Diff vs round 6: h exchange rides sc0+sc1 (MALL write-through / MALL read,
// no-allocate in L1/L2) so the barrier needs NO leader __threadfence --
// vmcnt(0) before the arrive-RMW IS the release, and readers always see the
// coherence point. Census/leader/done kept (RMW-contention reduction only).
// Arithmetic identical to round 6 (bit-identical results).
// ---------------------------------------------------------------------------
__global__ __launch_bounds__(256) void lstm_chunk(
    u16* __restrict__ hHi, u16* __restrict__ hLo,           // [L][2][128][512]
    const u16* __restrict__ whhHi, const u16* __restrict__ whhLo, // [L][2048][512] permuted
    const float* __restrict__ gx,                            // [L][tau][128][2048]
    const float* __restrict__ startsT,                       // [t][128]
    float* __restrict__ cT,                                  // [L][512][128]
    u16* __restrict__ ysHi, u16* __restrict__ ysLo,          // [L][tau][128][512]
    float* __restrict__ dout, unsigned* __restrict__ barZ, int t0)
{
    __shared__ __attribute__((aligned(16))) u16 sA[2][16384];  // [plane][kt][wcol][32k]
    __shared__ float zsm[4][144];
    __shared__ unsigned shLead, shNloc, shXC;

    const int tid  = threadIdx.x;
    const int wc   = blockIdx.x;         // 0..63 : 32 gate-cols
    const int eb   = blockIdx.y;         // 0..1  : 64-env half
    const int L    = blockIdx.z;
    const int wid  = tid >> 6, lane = tid & 63;
    const int l15  = lane & 15, quad = lane >> 4;
    const int ebase = eb*64;
    const int e    = ebase + wid*16 + l15;       // this lane's env (as B row)

    unsigned xcc;
    asm("s_getreg_b32 %0, hwreg(HW_REG_XCC_ID)" : "=s"(xcc));
    xcc &= 7u;
    const int ch = t0 >> 6;
    unsigned* ARRb  = barZ;
    unsigned* DONEb = barZ + 65536;
    unsigned* RCNTb = barZ + 73728;
    unsigned* SBARb = barZ + 74752;
    unsigned* XCNTb = barZ + 74880;

    // ---- leader election + per-XCD census (once per chunk). XCNT add is
    // drained (vmcnt 0) before SBAR arrive so SBAR==256 => all XCNT adds done.
    if (tid == 0){
        unsigned r = a_add(&RCNTb[(ch*8 + (int)xcc)*16]);
        shLead = (r == 0u) ? 1u : 0u;
        if (r == 0u){
            a_add(&XCNTb[ch*16]);
            asm volatile("s_waitcnt vmcnt(0)" ::: "memory");
        }
        a_add(&SBARb[ch*16]);
        while (a_ld(&SBARb[ch*16]) < 256u) __builtin_amdgcn_s_sleep(2);
        shNloc = a_ld(&RCNTb[(ch*8 + (int)xcc)*16]);
        shXC   = a_ld(&XCNTb[ch*16]);
    }

    // ---- stage Whh' panel ONCE: 32 wcols x 512 k x hi/lo = 64 KB
    {
        const size_t wbase = (size_t)L*1048576 + (size_t)(wc*32)*512;
        #pragma unroll
        for (int i = 0; i < 16; ++i){
            int f = tid + i*256;          // 0..4095
            int pl = f >> 11;
            int r2 = f & 2047;
            int wcol = r2 >> 6, ksg = r2 & 63;
            const u16* src = (pl ? whhLo : whhHi) + wbase + (size_t)wcol*512 + ksg*8;
            int dst = (ksg>>2)*1024 + wcol*32 + (ksg&3)*8;
            *(short8*)(sA[pl] + dst) = *(const short8*)src;
        }
    }
    __syncthreads();
    const unsigned lead = shLead, nloc = shNloc, xcnt = shXC;

    // ---- cT in registers for the whole chunk (block-stationary ownership)
    const int u0 = wc*8 + quad;          // mt=0 unit
    const int u1 = wc*8 + 4 + quad;      // mt=1 unit
    const size_t ci0 = (size_t)L*65536 + (size_t)u0*128 + e;
    const size_t ci1 = (size_t)L*65536 + (size_t)u1*128 + e;
    float c0 = cT[ci0];
    float c1 = cT[ci1];

    const size_t hrowOff = (size_t)e*512 + quad*8;
    const size_t gxbase  = ((size_t)L*CR + e)*2048 + wc*32 + quad*4;

    for (int tau = 0; tau < CH; ++tau){
        const int t = t0 + tau;
        const int p = t & 1;

        // gx (HBM) + mask loads issue first; latency hides under the K-loop.
        // gx lines now STAY in L2 across steps (no more per-step buffer_inv).
        const float* gp = gx + gxbase + (size_t)tau*(128*2048);
        float4 gv0 = *(const float4*)(gp);
        float4 gv1 = *(const float4*)(gp + 16);
        const float mn = (t < TT-1) ? (1.0f - startsT[(t+1)*128 + e]) : 1.0f;

        // ---- K loop, 4-deep pipelined MALL h-loads. vmcnt retires in issue
        // order: waiting to <=6 outstanding always retires the consumed pair,
        // regardless of where the compiler placed its own gx/mask loads.
        const u16* hHiP = hHi + (size_t)(L*2+p)*65536 + hrowOff;
        const u16* hLoP = hLo + (size_t)(L*2+p)*65536 + hrowOff;
        short8 pbh[4], pbl[4];
        #pragma unroll
        for (int i = 0; i < 4; ++i){
            pbh[i] = ld_mall(hHiP + i*32);
            pbl[i] = ld_mall(hLoP + i*32);
        }
        f32x4 acc0 = (f32x4){0.f,0.f,0.f,0.f};
        f32x4 acc1 = (f32x4){0.f,0.f,0.f,0.f};
        #pragma unroll
        for (int kt = 0; kt < 16; ++kt){
            if (kt < 13)      asm volatile("s_waitcnt vmcnt(6)" ::: "memory");
            else if (kt==13)  asm volatile("s_waitcnt vmcnt(4)" ::: "memory");
            else if (kt==14)  asm volatile("s_waitcnt vmcnt(2)" ::: "memory");
            else              asm volatile("s_waitcnt vmcnt(0)" ::: "memory");
            __builtin_amdgcn_sched_barrier(0);
            short8 bh = pbh[kt & 3];
            short8 bl = pbl[kt & 3];
            int a0 = kt*1024 + l15*32 + quad*8;          // mt=0 rows l15, mt=1 rows 16+l15
            short8 ah0 = *(const short8*)(sA[0] + a0);
            short8 al0 = *(const short8*)(sA[1] + a0);
            short8 ah1 = *(const short8*)(sA[0] + a0 + 512);
            short8 al1 = *(const short8*)(sA[1] + a0 + 512);
            acc0 = mfma16(ah0, bh, acc0);
            acc0 = mfma16(ah0, bl, acc0);
            acc0 = mfma16(al0, bh, acc0);
            acc1 = mfma16(ah1, bh, acc1);
            acc1 = mfma16(ah1, bl, acc1);
            acc1 = mfma16(al1, bh, acc1);
            if (kt < 12){
                pbh[kt & 3] = ld_mall(hHiP + (kt+4)*32);
                pbl[kt & 3] = ld_mall(hLoP + (kt+4)*32);
            }
        }

        // ---- gates -> state update (env = l15, unit = quad, gates = regs)
        {
            float ii = sigm(acc0[0] + gv0.x);
            float ff = sigm(acc0[1] + gv0.y);
            float gg = tanh_f(acc0[2] + gv0.z);
            float oo = sigm(acc0[3] + gv0.w);
            float cn = ff*c0 + ii*gg;
            float hn = oo * tanh_f(cn);
            c0 = cn * mn;
            zsm[wid][l15*8 + quad] = hn;
            zsm[wid][128 + l15] = mn;
            if (t == TT-1) {
                dout[(size_t)(3+2*L)*NN + (size_t)e*512 + u0] = hn;
                dout[(size_t)(4+2*L)*NN + (size_t)e*512 + u0] = cn;
            }
        }
        {
            float ii = sigm(acc1[0] + gv1.x);
            float ff = sigm(acc1[1] + gv1.y);
            float gg = tanh_f(acc1[2] + gv1.z);
            float oo = sigm(acc1[3] + gv1.w);
            float cn = ff*c1 + ii*gg;
            float hn = oo * tanh_f(cn);
            c1 = cn * mn;
            zsm[wid][l15*8 + 4 + quad] = hn;
            if (t == TT-1) {
                dout[(size_t)(3+2*L)*NN + (size_t)e*512 + u1] = hn;
                dout[(size_t)(4+2*L)*NN + (size_t)e*512 + u1] = cn;
            }
        }
        __syncthreads();

        // ---- coalesced h / ys writes: role = quad (0:hHi 1:hLo 2:ysHi 3:ysLo)
        // h planes go write-through to MALL (sc0 sc1); ys stays plain/cached
        // (consumed only after kernel end -> boundary flush covers it).
        {
            const int role = quad;
            const int e2 = l15;
            const int eg = ebase + wid*16 + e2;
            float v[8];
            #pragma unroll
            for (int j = 0; j < 8; ++j) v[j] = zsm[wid][e2*8 + j];
            const float mn2 = zsm[wid][128 + e2];
            short8 pk;
            if (role < 2) {
                #pragma unroll
                for (int j = 0; j < 8; ++j){
                    float hm = v[j] * mn2;
                    u16 h = f2bf(hm);
                    pk[j] = (short)(role == 0 ? h : f2bf(hm - bf2f(h)));
                }
                u16* dst = (role == 0 ? hHi : hLo)
                         + (size_t)(L*2 + (1-p))*65536 + (size_t)eg*512 + wc*8;
                st_mall(dst, pk);
            } else {
                #pragma unroll
                for (int j = 0; j < 8; ++j){
                    u16 h = f2bf(v[j]);
                    pk[j] = (short)(role == 2 ? h : f2bf(v[j] - bf2f(h)));
                }
                u16* dst = (role == 2 ? ysHi : ysLo)
                         + ((size_t)L*CR + (size_t)tau*128 + eg)*512 + wc*8;
                *(short8*)dst = pk;
            }
        }

        // ---- device barrier, fence-free: vmcnt(0) drains the write-through
        // h stores to MALL BEFORE the arrive-RMW issues => arrival implies
        // this block's h is globally visible. done==xcnt gates all readers.
        if (tau < CH-1){
            asm volatile("s_waitcnt vmcnt(0)" ::: "memory");  // h at MALL
            __syncthreads();
            if (tid == 0){
                unsigned* ap = &ARRb[((size_t)t*8 + xcc)*16];
                unsigned* dp = &DONEb[(size_t)t*16];
                a_add(ap);
                if (lead){
                    while (a_ld(ap) < nloc) __builtin_amdgcn_s_sleep(1);
                    a_add(dp);
                }
                while (a_ld(dp) < xcnt) __builtin_amdgcn_s_sleep(1);
            }
            __syncthreads();
            asm volatile("" ::: "memory");
        }
    }

    cT[ci0] = c0;
    cT[ci1] = c1;
}

// ---------------------------------------------------------------------------
// heads: chunk row m = tau*128 + e  ->  n = e*TT + t0 + tau
// ---------------------------------------------------------------------------
__global__ __launch_bounds__(256) void head_pi(
    const u16* __restrict__ latHi, const u16* __restrict__ latLo,
    const float* __restrict__ actor_w, const float* __restrict__ actor_b,
    float* __restrict__ dout, int t0)
{
    __shared__ float latS[16*516];
    __shared__ float lg[16*36];
    const int tid = threadIdx.x;
    const long r0 = (long)blockIdx.x * 16;
    {
        int rr = tid >> 4, seg = tid & 15;
        const u16* ph = latHi + (r0 + rr)*512 + seg*32;
        const u16* pl = latLo + (r0 + rr)*512 + seg*32;
        float* dst = latS + rr*516 + seg*32;
        #pragma unroll
        for (int ii = 0; ii < 4; ++ii){
            short8 vh = *(const short8*)(ph + ii*8);
            short8 vl = *(const short8*)(pl + ii*8);
            #pragma unroll
            for (int jj = 0; jj < 8; ++jj)
                dst[ii*8+jj] = bf2f((u16)vh[jj]) + bf2f((u16)vl[jj]);
        }
    }
    __syncthreads();
    {
        int rr = tid >> 4, a0 = (tid & 15)*2;
        const float4* lrow = (const float4*)(latS + rr*516);
        float acc0 = actor_b[a0], acc1 = actor_b[a0+1];
        for (int kq = 0; kq < 128; ++kq){
            float4 lv = lrow[kq];
            float4 w0 = ((const float4*)actor_w)[(a0  )*128 + kq];
            float4 w1 = ((const float4*)actor_w)[(a0+1)*128 + kq];
            acc0 += lv.x*w0.x + lv.y*w0.y + lv.z*w0.z + lv.w*w0.w;
            acc1 += lv.x*w1.x + lv.y*w1.y + lv.z*w1.z + lv.w*w1.w;
        }
        lg[rr*36 + a0]   = acc0;
        lg[rr*36 + a0+1] = acc1;
    }
    __syncthreads();
    if (tid < 16){
        float mx = -INFINITY; int am = 0;
        #pragma unroll
        for (int a = 0; a < AA; ++a){
            float v = lg[tid*36 + a];
            if (v > mx){ mx = v; am = a; }
        }
        float se = 0.f;
        #pragma unroll
        for (int a = 0; a < AA; ++a) se += expf(lg[tid*36 + a] - mx);
        long row = r0 + tid;
        long n = (row & 127)*TT + t0 + (row >> 7);
        dout[n] = (float)am;
        dout[2L*NN + n] = -logf(se);
    }
}

__global__ __launch_bounds__(256) void head_vf(
    const u16* __restrict__ latHi, const u16* __restrict__ latLo,
    const float* __restrict__ critic_w, const float* __restrict__ critic_b,
    float* __restrict__ dout, int t0)
{
    __shared__ float part[256];
    const int tid = threadIdx.x;
    const long r0 = (long)blockIdx.x * 32;
    int rr = tid >> 3, seg = tid & 7;
    const u16* ph = latHi + (r0 + rr)*512 + seg*64;
    const u16* pl = latLo + (r0 + rr)*512 + seg*64;
    float acc = 0.f;
    #pragma unroll
    for (int ii = 0; ii < 8; ++ii){
        short8 vh = *(const short8*)(ph + ii*8);
        short8 vl = *(const short8*)(pl + ii*8);
        #pragma unroll
        for (int jj = 0; jj < 8; ++jj){
            float lv = bf2f((u16)vh[jj]) + bf2f((u16)vl[jj]);
            acc += lv * critic_w[seg*64 + ii*8 + jj];
        }
    }
    part[tid] = acc;
    __syncthreads();
    if (tid < 32){
        float v = critic_b[0];
        #pragma unroll
        for (int s = 0; s < 8; ++s) v += part[tid*8 + s];
        long row = r0 + tid;
        long n = (row & 127)*TT + t0 + (row >> 7);
        dout[(long)NN + n] = v;
    }
}

// ---------------------------------------------------------------------------
extern "C" void kernel_launch(void* const* d_in, const int* in_sizes, int n_in,
                              void* d_out, int out_size, void* d_ws, size_t ws_size,
                              hipStream_t stream) {
    const float* features = (const float*)d_in[0];
    const float* starts   = (const float*)d_in[1];
    const float* h0_pi = (const float*)d_in[2];
    const float* c0_pi = (const float*)d_in[3];
    const float* h0_vf = (const float*)d_in[4];
    const float* c0_vf = (const float*)d_in[5];
    const float* Wih_pi = (const float*)d_in[6];
    const float* Whh_pi = (const float*)d_in[7];
    const float* bih_pi = (const float*)d_in[8];
    const float* bhh_pi = (const float*)d_in[9];
    const float* Wih_vf = (const float*)d_in[10];
    const float* Whh_vf = (const float*)d_in[11];
    const float* bih_vf = (const float*)d_in[12];
    const float* bhh_vf = (const float*)d_in[13];
    const float* pol_w1 = (const float*)d_in[14];
    const float* pol_b1 = (const float*)d_in[15];
    const float* pol_w2 = (const float*)d_in[16];
    const float* pol_b2 = (const float*)d_in[17];
    const float* val_w1 = (const float*)d_in[18];
    const float* val_b1 = (const float*)d_in[19];
    const float* val_w2 = (const float*)d_in[20];
    const float* val_b2 = (const float*)d_in[21];
    const float* actor_w  = (const float*)d_in[22];
    const float* actor_b  = (const float*)d_in[23];
    const float* critic_w = (const float*)d_in[24];
    const float* critic_b = (const float*)d_in[25];
    float* out = (float*)d_out;

    size_t off = 0;
    auto alloc = [&](size_t b) {
        void* p = (char*)d_ws + off;
        off += (b + 255) & ~(size_t)255;
        return p;
    };
    u16* wihHi = (u16*)alloc(2L*2048*512*2);
    u16* wihLo = (u16*)alloc(2L*2048*512*2);
    u16* whhHi = (u16*)alloc(2L*2048*512*2);
    u16* whhLo = (u16*)alloc(2L*2048*512*2);
    float* biasP = (float*)alloc(2L*2048*4);
    u16* mHi = (u16*)alloc(4L*262144*2);
    u16* mLo = (u16*)alloc(4L*262144*2);
    float* biasM = (float*)alloc(4L*512*4);
    u16* hHi = (u16*)alloc(2L*2*128*512*2);
    u16* hLo = (u16*)alloc(2L*2*128*512*2);
    float* cT  = (float*)alloc(2L*128*512*4);
    float* startsT = (float*)alloc((size_t)NN*4);
    unsigned* barZ = (unsigned*)alloc((size_t)BARZ_N*4);
    u16* ysHi = (u16*)alloc(2L*CR*512*2);
    u16* ysLo = (u16*)alloc(2L*CR*512*2);
    u16* hidHi = (u16*)alloc(2L*CR*512*2);
    u16* hidLo = (u16*)alloc(2L*CR*512*2);
    u16* latHi = (u16*)alloc(2L*CR*512*2);
    u16* latLo = (u16*)alloc(2L*CR*512*2);
    float* gxF = (float*)alloc(2L*CR*2048*4);     // [L][tau][128][2048], 134 MB
    const long gxZ = (long)CR*2048;               // per-net stride
    const long pZ  = (long)CR*512;                // plane per-net stride

    prep_lstm_w<<<dim3(8192), dim3(256), 0, stream>>>(
        Wih_pi, Whh_pi, bih_pi, bhh_pi, Wih_vf, Whh_vf, bih_vf, bhh_vf,
        wihHi, wihLo, whhHi, whhLo, biasP);
    prep_mlp_w<<<dim3(4096), dim3(256), 0, stream>>>(
        pol_w1, val_w1, pol_w2, val_w2, pol_b1, val_b1, pol_b2, val_b2,
        mHi, mLo, biasM);
    init_state_k<<<dim3(512), dim3(256), 0, stream>>>(
        h0_pi, c0_pi, h0_vf, c0_vf, starts, hHi, hLo, cT, startsT, barZ);

    for (int t0 = 0; t0 < TT; t0 += CH) {
        // gx[L][tau][e][2048] = x @ Wih'^T + (bih+bhh); out row m = tau*128+e,
        // feature row = e*512 + t0 + tau  -> arow = (m&127)*512 + (m>>7) + t0
        gemm_k512<0,0><<<dim3(CR/128, 16, 2), dim3(256), 0, stream>>>(
            features, nullptr, nullptr, 0L,
            7, 1, 512, t0,
            wihHi, wihLo, 1048576L,
            biasP, 2048L,
            gxF, gxZ, 2048,
            nullptr, nullptr, 0L);
        // 64 recurrent steps in ONE persistent plain launch (fence-free sync)
        lstm_chunk<<<dim3(64, 2, 2), dim3(256), 0, stream>>>(
            hHi, hLo, whhHi, whhLo, gxF, startsT, cT, ysHi, ysLo,
            out, barZ, t0);
        // MLP layers on the chunk (rows = tau*128+e, identity map)
        gemm_k512<1,1><<<dim3(CR/128, 4, 2), dim3(256), 0, stream>>>(
            nullptr, ysHi, ysLo, pZ,
            30, 0, 1, 0,
            mHi, mLo, 262144L,
            biasM, 512L,
            nullptr, 0L, 0,
            hidHi, hidLo, pZ);
        gemm_k512<1,2><<<dim3(CR/128, 4, 2), dim3(256), 0, stream>>>(
            nullptr, hidHi, hidLo, pZ,
            30, 0, 1, 0,
            mHi + 2L*262144, mLo + 2L*262144, 262144L,
            biasM + 1024, 512L,
            nullptr, 0L, 0,
            latHi, latLo, pZ);
        head_pi<<<dim3(CR/16), dim3(256), 0, stream>>>(
            latHi, latLo, actor_w, actor_b, out, t0);
        head_vf<<<dim3(CR/32), dim3(256), 0, stream>>>(
            latHi + pZ, latLo + pZ, critic_w, critic_b, out, t0);
    }
}

// Round 8
// 6712.897 us; speedup vs baseline: 4.1056x; 1.0154x over previous
//
#include <hip/hip_runtime.h>
#include <math.h>

#define BB 128
#define TT 512
#define DD 512
#define HH 512
#define NN (BB*TT)   // 65536
#define PP 512
#define AA 32
#define CH 64        // timesteps per chunk
#define CR (BB*CH)   // rows per chunk per net = 8192

typedef unsigned short u16;
typedef unsigned int   u32;
typedef __attribute__((ext_vector_type(8))) short short8;
typedef __attribute__((ext_vector_type(4))) float f32x4;

__device__ __forceinline__ u16 f2bf(float f){
    u32 x = __float_as_uint(f);
    u32 r = (x + 0x7fffu + ((x >> 16) & 1u)) >> 16;   // RNE
    return (u16)r;
}
__device__ __forceinline__ float bf2f(u16 u){
    return __uint_as_float(((u32)u) << 16);
}
__device__ __forceinline__ f32x4 mfma16(short8 a, short8 b, f32x4 c){
    return __builtin_amdgcn_mfma_f32_16x16x32_bf16(a, b, c, 0, 0, 0);
}
__device__ __forceinline__ float sigm(float x){
    return 1.f/(1.f + __expf(-x));
}
__device__ __forceinline__ float tanh_f(float x){
    return 1.f - 2.f/(1.f + __expf(2.f*x));
}

// MALL-coherent h path: sc0 (L1 bypass/no-alloc) + sc1 (L2 bypass/no-alloc).
// Loads read the coherence point; stores write through to it. h lines are
// never allocated in any L1/L2, so the step barrier needs NO wbl2/inv:
// vmcnt(0) == release (stores acked at MALL before the arrive-RMW issues).
// NOTE: untracked by compiler vmcnt bookkeeping -> explicit s_waitcnt.
__device__ __forceinline__ short8 ld_mall(const u16* p){
    short8 r;
    asm volatile("global_load_dwordx4 %0, %1, off sc0 sc1"
                 : "=&v"(r) : "v"(p) : "memory");
    return r;
}
__device__ __forceinline__ void st_mall(u16* p, short8 v){
    asm volatile("global_store_dwordx4 %0, %1, off sc0 sc1"
                 :: "v"(p), "v"(v) : "memory");
}

__device__ __forceinline__ unsigned a_add(unsigned* p){
    return __hip_atomic_fetch_add(p, 1u, __ATOMIC_RELAXED, __HIP_MEMORY_SCOPE_AGENT);
}
__device__ __forceinline__ unsigned a_ld(unsigned* p){
    return __hip_atomic_load(p, __ATOMIC_RELAXED, __HIP_MEMORY_SCOPE_AGENT);
}

// barZ layout (u32 indices), all counters 64B-padded:
//   ARR(t,x)  = (t*8+x)*16            [0,      65536)
//   DONE(t)   = 65536 + t*16          [65536,  73728)
//   RCNT(c,x) = 73728 + (c*8+x)*16    [73728,  74752)
//   SBAR(c)   = 74752 + c*16          [74752,  74880)
//   XCNT(c)   = 74880 + c*16          [74880,  75008)
#define BARZ_N 75264

// ---------------------------------------------------------------------------
// prep: permute+split LSTM weights. Both Wih and Whh PERMUTED: col c=u*4+g
// <- src row g*512+u. biasP permuted bih+bhh.
// ---------------------------------------------------------------------------
__global__ __launch_bounds__(256) void prep_lstm_w(
    const float* __restrict__ Wih_pi, const float* __restrict__ Whh_pi,
    const float* __restrict__ bih_pi, const float* __restrict__ bhh_pi,
    const float* __restrict__ Wih_vf, const float* __restrict__ Whh_vf,
    const float* __restrict__ bih_vf, const float* __restrict__ bhh_vf,
    u16* __restrict__ wihHi, u16* __restrict__ wihLo,
    u16* __restrict__ whhHi, u16* __restrict__ whhLo,
    float* __restrict__ biasP)
{
    long i = (long)blockIdx.x*256 + threadIdx.x;
    if (i >= 2L*2048*512) return;
    int L = (int)(i >> 20);
    int rem = (int)(i & 1048575);
    int c = rem >> 9, k = rem & 511;
    int u = c >> 2, g = c & 3;
    long src = (long)(g*512 + u)*512 + k;
    float wih = (L ? Wih_vf : Wih_pi)[src];
    float whh = (L ? Whh_vf : Whh_pi)[src];
    u16 h1 = f2bf(wih); wihHi[i] = h1; wihLo[i] = f2bf(wih - bf2f(h1));
    u16 h2 = f2bf(whh); whhHi[i] = h2; whhLo[i] = f2bf(whh - bf2f(h2));
    if (k == 0) {
        float b = (L ? bih_vf : bih_pi)[g*512+u] + (L ? bhh_vf : bhh_pi)[g*512+u];
        biasP[L*2048 + c] = b;
    }
}

// prep MLP weight planes: mat 0=w1pi 1=w1vf 2=w2pi 3=w2vf
__global__ __launch_bounds__(256) void prep_mlp_w(
    const float* __restrict__ w1pi, const float* __restrict__ w1vf,
    const float* __restrict__ w2pi, const float* __restrict__ w2vf,
    const float* __restrict__ b1pi, const float* __restrict__ b1vf,
    const float* __restrict__ b2pi, const float* __restrict__ b2vf,
    u16* __restrict__ mHi, u16* __restrict__ mLo, float* __restrict__ biasM)
{
    long i = (long)blockIdx.x*256 + threadIdx.x;
    if (i >= 4L*262144) return;
    int mat = (int)(i >> 18);
    int rem = (int)(i & 262143);
    const float* src = mat==0 ? w1pi : mat==1 ? w1vf : mat==2 ? w2pi : w2vf;
    float v = src[rem];
    u16 h = f2bf(v); mHi[i] = h; mLo[i] = f2bf(v - bf2f(h));
    if (rem < 512) {
        const float* bs = mat==0 ? b1pi : mat==1 ? b1vf : mat==2 ? b2pi : b2vf;
        biasM[mat*512 + rem] = bs[rem];
    }
}

// init: h planes [L][p=0][e][u] pre-masked; cT transposed [L][u][e] pre-masked;
// startsT [t][e]; zero ALL barrier/rank counters (fresh every graph replay).
__global__ __launch_bounds__(256) void init_state_k(
    const float* __restrict__ h0_pi, const float* __restrict__ c0_pi,
    const float* __restrict__ h0_vf, const float* __restrict__ c0_vf,
    const float* __restrict__ starts,
    u16* __restrict__ hHi, u16* __restrict__ hLo, float* __restrict__ cT,
    float* __restrict__ startsT, unsigned* __restrict__ barZ)
{
    int i = blockIdx.x*256 + threadIdx.x;
    if (i < BARZ_N) barZ[i] = 0u;
    if (i < NN) {
        int e = i >> 9, t = i & 511;
        startsT[t*128 + e] = starts[i];
    }
    if (i >= 2*BB*HH) return;
    int L = i >> 16; int r = i & 65535;
    int e = r >> 9, u = r & 511;
    float m = 1.0f - starts[(long)e*TT];
    float h = (L ? h0_vf : h0_pi)[r] * m;
    float c = (L ? c0_vf : c0_pi)[r] * m;
    long hidx = (long)(L*2)*65536 + r;    // [L][parity=0][e][u]
    u16 hh = f2bf(h);
    hHi[hidx] = hh; hLo[hidx] = f2bf(h - bf2f(hh));
    cT[(long)L*65536 + (long)u*128 + e] = c;
}

// ---------------------------------------------------------------------------
// generic K=512 split-bf16 GEMM, tile 128x128, 256 threads (4 waves, 64x64)
// AM: 0 = A fp32 (converted in staging)   1 = A hi/lo planes
// row map: arow = (m>>rowSh)*rowOuterHi + (m&mask)*rowOuterLo + rowBase
// EM: 0 = +bias -> fp32 out   1 = +bias,relu -> planes   2 = +bias -> planes
// ---------------------------------------------------------------------------
template<int AM, int EM>
__global__ __launch_bounds__(256) void gemm_k512(
    const float* __restrict__ Afp,
    const u16* __restrict__ aHi, const u16* __restrict__ aLo, long aZ,
    int rowSh, int rowOuterHi, int rowOuterLo, int rowBase,
    const u16* __restrict__ bHi, const u16* __restrict__ bLo, long bZ,
    const float* __restrict__ bias, long biasZ,
    float* __restrict__ outF, long outFZ, int outLd,
    u16* __restrict__ oHi, u16* __restrict__ oLo, long oZ)
{
    __shared__ u16 sAh[5120], sAl[5120], sBh[5120], sBl[5120];  // 128 x 40 each
    const int tid = threadIdx.x;
    const int z = blockIdx.z;
    const long Mbase = (long)blockIdx.x * 128;
    const long Nbase = (long)blockIdx.y * 128;
    const int r2 = tid >> 1, half = tid & 1;
    const long mstage = Mbase + r2;
    const long arow = (mstage >> rowSh) * (long)rowOuterHi
                    + (mstage & (((long)1<<rowSh)-1)) * (long)rowOuterLo + rowBase;
    const long brow = Nbase + r2;
    const int wid = tid >> 6, lane = tid & 63;
    const int mh = wid & 1, nh = wid >> 1;
    const int l15 = lane & 15, quad = lane >> 4;

    f32x4 acc[4][4];
    #pragma unroll
    for (int i = 0; i < 4; ++i)
        #pragma unroll
        for (int j = 0; j < 4; ++j)
            acc[i][j] = (f32x4){0.f,0.f,0.f,0.f};

    const int sOffW = r2*40 + half*16;

    for (int kt = 0; kt < 16; ++kt) {
        const int k0 = kt*32;
        if constexpr (AM == 0) {
            const float* ap = Afp + arow*512 + k0 + half*16;
            float fv[16];
            #pragma unroll
            for (int q = 0; q < 4; ++q) *(float4*)(fv + q*4) = ((const float4*)ap)[q];
            short8 vh0, vh1, vl0, vl1;
            #pragma unroll
            for (int i = 0; i < 8; ++i){
                u16 h  = f2bf(fv[i]);   vh0[i] = (short)h;  vl0[i] = (short)f2bf(fv[i]   - bf2f(h));
                u16 h2 = f2bf(fv[8+i]); vh1[i] = (short)h2; vl1[i] = (short)f2bf(fv[8+i] - bf2f(h2));
            }
            *(short8*)(sAh + sOffW) = vh0; *(short8*)(sAh + sOffW + 8) = vh1;
            *(short8*)(sAl + sOffW) = vl0; *(short8*)(sAl + sOffW + 8) = vl1;
        } else {
            const u16* ph = aHi + (long)z*aZ + arow*512 + k0 + half*16;
            const u16* pl = aLo + (long)z*aZ + arow*512 + k0 + half*16;
            *(short8*)(sAh + sOffW) = *(const short8*)ph;
            *(short8*)(sAh + sOffW + 8) = *(const short8*)(ph + 8);
            *(short8*)(sAl + sOffW) = *(const short8*)pl;
            *(short8*)(sAl + sOffW + 8) = *(const short8*)(pl + 8);
        }
        {
            const u16* ph = bHi + (long)z*bZ + brow*512 + k0 + half*16;
            const u16* pl = bLo + (long)z*bZ + brow*512 + k0 + half*16;
            *(short8*)(sBh + sOffW) = *(const short8*)ph;
            *(short8*)(sBh + sOffW + 8) = *(const short8*)(ph + 8);
            *(short8*)(sBl + sOffW) = *(const short8*)pl;
            *(short8*)(sBl + sOffW + 8) = *(const short8*)(pl + 8);
        }
        __syncthreads();
        short8 bh[4], bl[4];
        #pragma unroll
        for (int nt = 0; nt < 4; ++nt){
            int bo = (nh*64 + nt*16 + l15)*40 + quad*8;
            bh[nt] = *(const short8*)(sBh + bo);
            bl[nt] = *(const short8*)(sBl + bo);
        }
        #pragma unroll
        for (int mt = 0; mt < 4; ++mt){
            int ao = (mh*64 + mt*16 + l15)*40 + quad*8;
            short8 ah = *(const short8*)(sAh + ao);
            short8 al = *(const short8*)(sAl + ao);
            #pragma unroll
            for (int nt = 0; nt < 4; ++nt){
                acc[mt][nt] = mfma16(ah, bh[nt], acc[mt][nt]);
                acc[mt][nt] = mfma16(ah, bl[nt], acc[mt][nt]);
                acc[mt][nt] = mfma16(al, bh[nt], acc[mt][nt]);
            }
        }
        __syncthreads();
    }
    #pragma unroll
    for (int nt = 0; nt < 4; ++nt){
        const long col = Nbase + nh*64 + nt*16 + l15;
        const float bv = bias[(long)z*biasZ + col];
        #pragma unroll
        for (int mt = 0; mt < 4; ++mt){
            const long rowm = Mbase + mh*64 + mt*16 + quad*4;
            #pragma unroll
            for (int rr = 0; rr < 4; ++rr){
                float v = acc[mt][nt][rr] + bv;
                const long m = rowm + rr;
                if constexpr (EM == 0) {
                    outF[(long)z*outFZ + m*(long)outLd + col] = v;
                } else {
                    if constexpr (EM == 1) v = fmaxf(v, 0.f);
                    u16 h = f2bf(v);
                    u16 l = f2bf(v - bf2f(h));
                    oHi[(long)z*oZ + m*512 + col] = h;
                    oLo[(long)z*oZ + m*512 + col] = l;
                }
            }
        }
    }
}

// ---------------------------------------------------------------------------
// Persistent LSTM chunk (round-7 base, VERIFIED at 582us/chunk). Diffs:
//  (1) K-loop issues ALL 16 h hi/lo pairs upfront (32 outstanding, group
//      vmcnt ladder 24/16/8/0). In-order retirement makes the ladder safe
//      regardless of prior outstanding stores/loads: waiting to N leaves
//      only the newest N h-loads unretired.
//  (2) Write phase remapped to WAVE roles (identical stores/values): waves
//      0/1 write h (write-through MALL) and drain vmcnt(0); waves 2/3 write
//      ys plain and never drain (ys consumed only after kernel end). Raw
//      s_barrier (no compiler-forced full drain) in the barrier block.
//  (3) Next step's gx/mask prefetch issues between arrive and spin, so its
//      HBM latency hides under the spin.
// Sync semantics identical to round 7 (vmcnt-release to MALL + counter gate;
// single barrier covers RAW+WAR via parity ping-pong). Bit-identical math.
// ---------------------------------------------------------------------------
__global__ __launch_bounds__(256) void lstm_chunk(
    u16* __restrict__ hHi, u16* __restrict__ hLo,           // [L][2][128][512]
    const u16* __restrict__ whhHi, const u16* __restrict__ whhLo, // [L][2048][512] permuted
    const float* __restrict__ gx,                            // [L][tau][128][2048]
    const float* __restrict__ startsT,                       // [t][128]
    float* __restrict__ cT,                                  // [L][512][128]
    u16* __restrict__ ysHi, u16* __restrict__ ysLo,          // [L][tau][128][512]
    float* __restrict__ dout, unsigned* __restrict__ barZ, int t0)
{
    __shared__ __attribute__((aligned(16))) u16 sA[2][16384];  // [plane][kt][wcol][32k]
    __shared__ float zsm[4][144];
    __shared__ unsigned shLead, shNloc, shXC;

    const int tid  = threadIdx.x;
    const int wc   = blockIdx.x;         // 0..63 : 32 gate-cols
    const int eb   = blockIdx.y;         // 0..1  : 64-env half
    const int L    = blockIdx.z;
    const int wid  = tid >> 6, lane = tid & 63;
    const int l15  = lane & 15, quad = lane >> 4;
    const int ebase = eb*64;
    const int e    = ebase + wid*16 + l15;       // this lane's env (as B row)

    unsigned xcc;
    asm("s_getreg_b32 %0, hwreg(HW_REG_XCC_ID)" : "=s"(xcc));
    xcc &= 7u;
    const int ch = t0 >> 6;
    unsigned* ARRb  = barZ;
    unsigned* DONEb = barZ + 65536;
    unsigned* RCNTb = barZ + 73728;
    unsigned* SBARb = barZ + 74752;
    unsigned* XCNTb = barZ + 74880;

    // ---- leader election + per-XCD census (once per chunk). XCNT add is
    // drained (vmcnt 0) before SBAR arrive so SBAR==256 => all XCNT adds done.
    if (tid == 0){
        unsigned r = a_add(&RCNTb[(ch*8 + (int)xcc)*16]);
        shLead = (r == 0u) ? 1u : 0u;
        if (r == 0u){
            a_add(&XCNTb[ch*16]);
            asm volatile("s_waitcnt vmcnt(0)" ::: "memory");
        }
        a_add(&SBARb[ch*16]);
        while (a_ld(&SBARb[ch*16]) < 256u) __builtin_amdgcn_s_sleep(2);
        shNloc = a_ld(&RCNTb[(ch*8 + (int)xcc)*16]);
        shXC   = a_ld(&XCNTb[ch*16]);
    }

    // ---- stage Whh' panel ONCE: 32 wcols x 512 k x hi/lo = 64 KB
    {
        const size_t wbase = (size_t)L*1048576 + (size_t)(wc*32)*512;
        #pragma unroll
        for (int i = 0; i < 16; ++i){
            int f = tid + i*256;          // 0..4095
            int pl = f >> 11;
            int r2 = f & 2047;
            int wcol = r2 >> 6, ksg = r2 & 63;
            const u16* src = (pl ? whhLo : whhHi) + wbase + (size_t)wcol*512 + ksg*8;
            int dst = (ksg>>2)*1024 + wcol*32 + (ksg&3)*8;
            *(short8*)(sA[pl] + dst) = *(const short8*)src;
        }
    }
    __syncthreads();
    const unsigned lead = shLead, nloc = shNloc, xcnt = shXC;

    // ---- cT in registers for the whole chunk (block-stationary ownership)
    const int u0 = wc*8 + quad;          // mt=0 unit
    const int u1 = wc*8 + 4 + quad;      // mt=1 unit
    const size_t ci0 = (size_t)L*65536 + (size_t)u0*128 + e;
    const size_t ci1 = (size_t)L*65536 + (size_t)u1*128 + e;
    float c0 = cT[ci0];
    float c1 = cT[ci1];

    const size_t hrowOff = (size_t)e*512 + quad*8;
    const size_t gxbase  = ((size_t)L*CR + e)*2048 + wc*32 + quad*4;

    // prefetch tau=0 gx + mask
    float4 gv0 = *(const float4*)(gx + gxbase);
    float4 gv1 = *(const float4*)(gx + gxbase + 16);
    float mn = (t0 < TT-1) ? (1.0f - startsT[(t0+1)*128 + e]) : 1.0f;

    for (int tau = 0; tau < CH; ++tau){
        const int t = t0 + tau;
        const int p = t & 1;

        // ---- K loop: ALL 32 h-loads issued upfront (MALL path). Group
        // vmcnt ladder: waiting to N leaves only the newest N h-loads
        // unretired (in-order retire), so pairs <= kt are guaranteed done.
        const u16* hHiP = hHi + (size_t)(L*2+p)*65536 + hrowOff;
        const u16* hLoP = hLo + (size_t)(L*2+p)*65536 + hrowOff;
        short8 pbh[16], pbl[16];
        #pragma unroll
        for (int i = 0; i < 16; ++i){
            pbh[i] = ld_mall(hHiP + i*32);
            pbl[i] = ld_mall(hLoP + i*32);
        }
        f32x4 acc0 = (f32x4){0.f,0.f,0.f,0.f};
        f32x4 acc1 = (f32x4){0.f,0.f,0.f,0.f};
        #pragma unroll
        for (int kt = 0; kt < 16; ++kt){
            if (kt == 0){
                asm volatile("s_waitcnt vmcnt(24)" ::: "memory");
                __builtin_amdgcn_sched_barrier(0);
            } else if (kt == 4){
                asm volatile("s_waitcnt vmcnt(16)" ::: "memory");
                __builtin_amdgcn_sched_barrier(0);
            } else if (kt == 8){
                asm volatile("s_waitcnt vmcnt(8)" ::: "memory");
                __builtin_amdgcn_sched_barrier(0);
            } else if (kt == 12){
                asm volatile("s_waitcnt vmcnt(0)" ::: "memory");
                __builtin_amdgcn_sched_barrier(0);
            }
            short8 bh = pbh[kt];
            short8 bl = pbl[kt];
            int a0 = kt*1024 + l15*32 + quad*8;          // mt=0 rows l15, mt=1 rows 16+l15
            short8 ah0 = *(const short8*)(sA[0] + a0);
            short8 al0 = *(const short8*)(sA[1] + a0);
            short8 ah1 = *(const short8*)(sA[0] + a0 + 512);
            short8 al1 = *(const short8*)(sA[1] + a0 + 512);
            acc0 = mfma16(ah0, bh, acc0);
            acc0 = mfma16(ah0, bl, acc0);
            acc0 = mfma16(al0, bh, acc0);
            acc1 = mfma16(ah1, bh, acc1);
            acc1 = mfma16(ah1, bl, acc1);
            acc1 = mfma16(al1, bh, acc1);
        }

        // ---- gates -> state update (env = l15, unit = quad, gates = regs)
        {
            float ii = sigm(acc0[0] + gv0.x);
            float ff = sigm(acc0[1] + gv0.y);
            float gg = tanh_f(acc0[2] + gv0.z);
            float oo = sigm(acc0[3] + gv0.w);
            float cn = ff*c0 + ii*gg;
            float hn = oo * tanh_f(cn);
            c0 = cn * mn;
            zsm[wid][l15*8 + quad] = hn;
            zsm[wid][128 + l15] = mn;
            if (t == TT-1) {
                dout[(size_t)(3+2*L)*NN + (size_t)e*512 + u0] = hn;
                dout[(size_t)(4+2*L)*NN + (size_t)e*512 + u0] = cn;
            }
        }
        {
            float ii = sigm(acc1[0] + gv1.x);
            float ff = sigm(acc1[1] + gv1.y);
            float gg = tanh_f(acc1[2] + gv1.z);
            float oo = sigm(acc1[3] + gv1.w);
            float cn = ff*c1 + ii*gg;
            float hn = oo * tanh_f(cn);
            c1 = cn * mn;
            zsm[wid][l15*8 + 4 + quad] = hn;
            if (t == TT-1) {
                dout[(size_t)(3+2*L)*NN + (size_t)e*512 + u1] = hn;
                dout[(size_t)(4+2*L)*NN + (size_t)e*512 + u1] = cn;
            }
        }
        __syncthreads();

        // ---- write phase, WAVE roles (identical stores/values to quad-role):
        // wave 0: hHi (MALL)  wave 1: hLo (MALL)  wave 2: ysHi  wave 3: ysLo
        {
            const int g2 = quad;          // env-group (was wid)
            const int e2 = l15;
            const int eg = ebase + g2*16 + e2;
            float v[8];
            #pragma unroll
            for (int j = 0; j < 8; ++j) v[j] = zsm[g2][e2*8 + j];
            const float mn2 = zsm[g2][128 + e2];
            short8 pk;
            if (wid < 2) {
                #pragma unroll
                for (int j = 0; j < 8; ++j){
                    float hm = v[j] * mn2;
                    u16 h = f2bf(hm);
                    pk[j] = (short)(wid == 0 ? h : f2bf(hm - bf2f(h)));
                }
                u16* dst = (wid == 0 ? hHi : hLo)
                         + (size_t)(L*2 + (1-p))*65536 + (size_t)eg*512 + wc*8;
                st_mall(dst, pk);
                asm volatile("s_waitcnt vmcnt(0)" ::: "memory");  // h at MALL
            } else {
                #pragma unroll
                for (int j = 0; j < 8; ++j){
                    u16 h = f2bf(v[j]);
                    pk[j] = (short)(wid == 2 ? h : f2bf(v[j] - bf2f(h)));
                }
                u16* dst = (wid == 2 ? ysHi : ysLo)
                         + ((size_t)L*CR + (size_t)tau*128 + eg)*512 + wc*8;
                *(short8*)dst = pk;                                // no drain
            }
        }

        // ---- device barrier, fence-free. Raw s_barrier: waves 0/1 already
        // drained their h stores; waves 2/3's ys stores need no ordering.
        __builtin_amdgcn_s_barrier();
        if (tau < CH-1){
            if (tid == 0) a_add(&ARRb[((size_t)t*8 + xcc)*16]);
            // prefetch next step's gx + mask: HBM latency hides under spin
            const float* gpn = gx + gxbase + (size_t)(tau+1)*(128*2048);
            gv0 = *(const float4*)(gpn);
            gv1 = *(const float4*)(gpn + 16);
            mn = (t+1 < TT-1) ? (1.0f - startsT[(t+2)*128 + e]) : 1.0f;
            if (tid == 0){
                unsigned* ap = &ARRb[((size_t)t*8 + xcc)*16];
                unsigned* dp = &DONEb[(size_t)t*16];
                if (lead){
                    while (a_ld(ap) < nloc) __builtin_amdgcn_s_sleep(1);
                    a_add(dp);
                }
                while (a_ld(dp) < xcnt) __builtin_amdgcn_s_sleep(1);
            }
            __builtin_amdgcn_s_barrier();
            asm volatile("" ::: "memory");
        }
    }

    cT[ci0] = c0;
    cT[ci1] = c1;
}

// ---------------------------------------------------------------------------
// heads: chunk row m = tau*128 + e  ->  n = e*TT + t0 + tau
// ---------------------------------------------------------------------------
__global__ __launch_bounds__(256) void head_pi(
    const u16* __restrict__ latHi, const u16* __restrict__ latLo,
    const float* __restrict__ actor_w, const float* __restrict__ actor_b,
    float* __restrict__ dout, int t0)
{
    __shared__ float latS[16*516];
    __shared__ float lg[16*36];
    const int tid = threadIdx.x;
    const long r0 = (long)blockIdx.x * 16;
    {
        int rr = tid >> 4, seg = tid & 15;
        const u16* ph = latHi + (r0 + rr)*512 + seg*32;
        const u16* pl = latLo + (r0 + rr)*512 + seg*32;
        float* dst = latS + rr*516 + seg*32;
        #pragma unroll
        for (int ii = 0; ii < 4; ++ii){
            short8 vh = *(const short8*)(ph + ii*8);
            short8 vl = *(const short8*)(pl + ii*8);
            #pragma unroll
            for (int jj = 0; jj < 8; ++jj)
                dst[ii*8+jj] = bf2f((u16)vh[jj]) + bf2f((u16)vl[jj]);
        }
    }
    __syncthreads();
    {
        int rr = tid >> 4, a0 = (tid & 15)*2;
        const float4* lrow = (const float4*)(latS + rr*516);
        float acc0 = actor_b[a0], acc1 = actor_b[a0+1];
        for (int kq = 0; kq < 128; ++kq){
            float4 lv = lrow[kq];
            float4 w0 = ((const float4*)actor_w)[(a0  )*128 + kq];
            float4 w1 = ((const float4*)actor_w)[(a0+1)*128 + kq];
            acc0 += lv.x*w0.x + lv.y*w0.y + lv.z*w0.z + lv.w*w0.w;
            acc1 += lv.x*w1.x + lv.y*w1.y + lv.z*w1.z + lv.w*w1.w;
        }
        lg[rr*36 + a0]   = acc0;
        lg[rr*36 + a0+1] = acc1;
    }
    __syncthreads();
    if (tid < 16){
        float mx = -INFINITY; int am = 0;
        #pragma unroll
        for (int a = 0; a < AA; ++a){
            float v = lg[tid*36 + a];
            if (v > mx){ mx = v; am = a; }
        }
        float se = 0.f;
        #pragma unroll
        for (int a = 0; a < AA; ++a) se += expf(lg[tid*36 + a] - mx);
        long row = r0 + tid;
        long n = (row & 127)*TT + t0 + (row >> 7);
        dout[n] = (float)am;
        dout[2L*NN + n] = -logf(se);
    }
}

__global__ __launch_bounds__(256) void head_vf(
    const u16* __restrict__ latHi, const u16* __restrict__ latLo,
    const float* __restrict__ critic_w, const float* __restrict__ critic_b,
    float* __restrict__ dout, int t0)
{
    __shared__ float part[256];
    const int tid = threadIdx.x;
    const long r0 = (long)blockIdx.x * 32;
    int rr = tid >> 3, seg = tid & 7;
    const u16* ph = latHi + (r0 + rr)*512 + seg*64;
    const u16* pl = latLo + (r0 + rr)*512 + seg*64;
    float acc = 0.f;
    #pragma unroll
    for (int ii = 0; ii < 8; ++ii){
        short8 vh = *(const short8*)(ph + ii*8);
        short8 vl = *(const short8*)(pl + ii*8);
        #pragma unroll
        for (int jj = 0; jj < 8; ++jj){
            float lv = bf2f((u16)vh[jj]) + bf2f((u16)vl[jj]);
            acc += lv * critic_w[seg*64 + ii*8 + jj];
        }
    }
    part[tid] = acc;
    __syncthreads();
    if (tid < 32){
        float v = critic_b[0];
        #pragma unroll
        for (int s = 0; s < 8; ++s) v += part[tid*8 + s];
        long row = r0 + tid;
        long n = (row & 127)*TT + t0 + (row >> 7);
        dout[(long)NN + n] = v;
    }
}

// ---------------------------------------------------------------------------
extern "C" void kernel_launch(void* const* d_in, const int* in_sizes, int n_in,
                              void* d_out, int out_size, void* d_ws, size_t ws_size,
                              hipStream_t stream) {
    const float* features = (const float*)d_in[0];
    const float* starts   = (const float*)d_in[1];
    const float* h0_pi = (const float*)d_in[2];
    const float* c0_pi = (const float*)d_in[3];
    const float* h0_vf = (const float*)d_in[4];
    const float* c0_vf = (const float*)d_in[5];
    const float* Wih_pi = (const float*)d_in[6];
    const float* Whh_pi = (const float*)d_in[7];
    const float* bih_pi = (const float*)d_in[8];
    const float* bhh_pi = (const float*)d_in[9];
    const float* Wih_vf = (const float*)d_in[10];
    const float* Whh_vf = (const float*)d_in[11];
    const float* bih_vf = (const float*)d_in[12];
    const float* bhh_vf = (const float*)d_in[13];
    const float* pol_w1 = (const float*)d_in[14];
    const float* pol_b1 = (const float*)d_in[15];
    const float* pol_w2 = (const float*)d_in[16];
    const float* pol_b2 = (const float*)d_in[17];
    const float* val_w1 = (const float*)d_in[18];
    const float* val_b1 = (const float*)d_in[19];
    const float* val_w2 = (const float*)d_in[20];
    const float* val_b2 = (const float*)d_in[21];
    const float* actor_w  = (const float*)d_in[22];
    const float* actor_b  = (const float*)d_in[23];
    const float* critic_w = (const float*)d_in[24];
    const float* critic_b = (const float*)d_in[25];
    float* out = (float*)d_out;

    size_t off = 0;
    auto alloc = [&](size_t b) {
        void* p = (char*)d_ws + off;
        off += (b + 255) & ~(size_t)255;
        return p;
    };
    u16* wihHi = (u16*)alloc(2L*2048*512*2);
    u16* wihLo = (u16*)alloc(2L*2048*512*2);
    u16* whhHi = (u16*)alloc(2L*2048*512*2);
    u16* whhLo = (u16*)alloc(2L*2048*512*2);
    float* biasP = (float*)alloc(2L*2048*4);
    u16* mHi = (u16*)alloc(4L*262144*2);
    u16* mLo = (u16*)alloc(4L*262144*2);
    float* biasM = (float*)alloc(4L*512*4);
    u16* hHi = (u16*)alloc(2L*2*128*512*2);
    u16* hLo = (u16*)alloc(2L*2*128*512*2);
    float* cT  = (float*)alloc(2L*128*512*4);
    float* startsT = (float*)alloc((size_t)NN*4);
    unsigned* barZ = (unsigned*)alloc((size_t)BARZ_N*4);
    u16* ysHi = (u16*)alloc(2L*CR*512*2);
    u16* ysLo = (u16*)alloc(2L*CR*512*2);
    u16* hidHi = (u16*)alloc(2L*CR*512*2);
    u16* hidLo = (u16*)alloc(2L*CR*512*2);
    u16* latHi = (u16*)alloc(2L*CR*512*2);
    u16* latLo = (u16*)alloc(2L*CR*512*2);
    float* gxF = (float*)alloc(2L*CR*2048*4);     // [L][tau][128][2048], 134 MB
    const long gxZ = (long)CR*2048;               // per-net stride
    const long pZ  = (long)CR*512;                // plane per-net stride

    prep_lstm_w<<<dim3(8192), dim3(256), 0, stream>>>(
        Wih_pi, Whh_pi, bih_pi, bhh_pi, Wih_vf, Whh_vf, bih_vf, bhh_vf,
        wihHi, wihLo, whhHi, whhLo, biasP);
    prep_mlp_w<<<dim3(4096), dim3(256), 0, stream>>>(
        pol_w1, val_w1, pol_w2, val_w2, pol_b1, val_b1, pol_b2, val_b2,
        mHi, mLo, biasM);
    init_state_k<<<dim3(512), dim3(256), 0, stream>>>(
        h0_pi, c0_pi, h0_vf, c0_vf, starts, hHi, hLo, cT, startsT, barZ);

    for (int t0 = 0; t0 < TT; t0 += CH) {
        // gx[L][tau][e][2048] = x @ Wih'^T + (bih+bhh); out row m = tau*128+e,
        // feature row = e*512 + t0 + tau  -> arow = (m&127)*512 + (m>>7) + t0
        gemm_k512<0,0><<<dim3(CR/128, 16, 2), dim3(256), 0, stream>>>(
            features, nullptr, nullptr, 0L,
            7, 1, 512, t0,
            wihHi, wihLo, 1048576L,
            biasP, 2048L,
            gxF, gxZ, 2048,
            nullptr, nullptr, 0L);
        // 64 recurrent steps in ONE persistent plain launch (fence-free sync)
        lstm_chunk<<<dim3(64, 2, 2), dim3(256), 0, stream>>>(
            hHi, hLo, whhHi, whhLo, gxF, startsT, cT, ysHi, ysLo,
            out, barZ, t0);
        // MLP layers on the chunk (rows = tau*128+e, identity map)
        gemm_k512<1,1><<<dim3(CR/128, 4, 2), dim3(256), 0, stream>>>(
            nullptr, ysHi, ysLo, pZ,
            30, 0, 1, 0,
            mHi, mLo, 262144L,
            biasM, 512L,
            nullptr, 0L, 0,
            hidHi, hidLo, pZ);
        gemm_k512<1,2><<<dim3(CR/128, 4, 2), dim3(256), 0, stream>>>(
            nullptr, hidHi, hidLo, pZ,
            30, 0, 1, 0,
            mHi + 2L*262144, mLo + 2L*262144, 262144L,
            biasM + 1024, 512L,
            nullptr, 0L, 0,
            latHi, latLo, pZ);
        head_pi<<<dim3(CR/16), dim3(256), 0, stream>>>(
            latHi, latLo, actor_w, actor_b, out, t0);
        head_vf<<<dim3(CR/32), dim3(256), 0, stream>>>(
            latHi + pZ, latLo + pZ, critic_w, critic_b, out, t0);
    }
}